// Round 1
// baseline (757.782 us; speedup 1.0000x reference)
//
#include <hip/hip_runtime.h>
#include <hip/hip_bf16.h>

#define NN 50000
#define EE 800000
#define IN_DIM 256
#define HID 64
#define HEADS 6
#define D1 384            // HEADS*HID
#define OUT_DIM 32
#define NEG_SLOPE 0.2f

// ---------------- CSR build ----------------

__global__ void deg_init_kernel(int* __restrict__ deg) {
    int i = blockIdx.x * 256 + threadIdx.x;
    if (i < NN) deg[i] = 1;   // self-loop contributes 1
}

__global__ void hist_kernel(const int* __restrict__ dst, int* __restrict__ deg) {
    int i = blockIdx.x * 256 + threadIdx.x;
    if (i < EE) atomicAdd(&deg[dst[i]], 1);
}

__global__ __launch_bounds__(1024) void scan_kernel(const int* __restrict__ deg,
                                                    int* __restrict__ offsets,
                                                    int* __restrict__ cursor) {
    __shared__ int part[1024];
    int t = threadIdx.x;
    const int CH = 49;  // ceil(50000/1024)
    int lo = t * CH;
    int hi = lo + CH; if (hi > NN) hi = NN; if (lo > NN) lo = NN;
    int s = 0;
    for (int i = lo; i < hi; ++i) s += deg[i];
    part[t] = s;
    __syncthreads();
    for (int off = 1; off < 1024; off <<= 1) {
        int v = (t >= off) ? part[t - off] : 0;
        __syncthreads();
        part[t] += v;
        __syncthreads();
    }
    int run = (t == 0) ? 0 : part[t - 1];
    for (int i = lo; i < hi; ++i) {
        offsets[i] = run; cursor[i] = run;
        run += deg[i];
    }
    if (t == 1023) offsets[NN] = run;  // == EE+NN
}

__global__ void scatter_kernel(const int* __restrict__ src, const int* __restrict__ dst,
                               int* __restrict__ cursor, int* __restrict__ srcIdx) {
    int i = blockIdx.x * 256 + threadIdx.x;
    if (i >= EE + NN) return;
    int s, d;
    if (i < EE) { s = src[i]; d = dst[i]; }
    else        { s = i - EE; d = s; }
    int pos = atomicAdd(&cursor[d], 1);
    srcIdx[pos] = s;
}

// ---------------- GEMM1: H1 = x @ W1  (50000x256 @ 256x384) ----------------

__global__ __launch_bounds__(256) void gemm1_kernel(const float* __restrict__ A,
                                                    const float* __restrict__ B,
                                                    float* __restrict__ C) {
    __shared__ float As[16][64];
    __shared__ float Bs[16][64];
    int t  = threadIdx.x;
    int n0 = blockIdx.x * 64;   // 0..5 tiles of N=384
    int m0 = blockIdx.y * 64;
    int tx = t & 15, ty = t >> 4;
    int arow = t >> 2,  akk  = (t & 3) * 4;
    int brow = t >> 4,  bcol = (t & 15) * 4;
    float acc[4][4] = {};
    for (int k0 = 0; k0 < IN_DIM; k0 += 16) {
        float4 av = make_float4(0.f, 0.f, 0.f, 0.f);
        int gr = m0 + arow;
        if (gr < NN) av = *reinterpret_cast<const float4*>(&A[gr * IN_DIM + k0 + akk]);
        As[akk + 0][arow] = av.x; As[akk + 1][arow] = av.y;
        As[akk + 2][arow] = av.z; As[akk + 3][arow] = av.w;
        float4 bv = *reinterpret_cast<const float4*>(&B[(k0 + brow) * D1 + n0 + bcol]);
        *reinterpret_cast<float4*>(&Bs[brow][bcol]) = bv;
        __syncthreads();
#pragma unroll
        for (int k = 0; k < 16; ++k) {
            float4 a4 = *reinterpret_cast<const float4*>(&As[k][ty * 4]);
            float4 b4 = *reinterpret_cast<const float4*>(&Bs[k][tx * 4]);
            float aa[4] = {a4.x, a4.y, a4.z, a4.w};
            float bb[4] = {b4.x, b4.y, b4.z, b4.w};
#pragma unroll
            for (int i = 0; i < 4; ++i)
#pragma unroll
                for (int j = 0; j < 4; ++j) acc[i][j] += aa[i] * bb[j];
        }
        __syncthreads();
    }
#pragma unroll
    for (int i = 0; i < 4; ++i) {
        int gr = m0 + ty * 4 + i;
        if (gr < NN) {
            float4 v = make_float4(acc[i][0], acc[i][1], acc[i][2], acc[i][3]);
            *reinterpret_cast<float4*>(&C[gr * D1 + n0 + tx * 4]) = v;
        }
    }
}

// ---------------- per-node attention coefficients, layer 1 ----------------

__global__ __launch_bounds__(256) void avec1_kernel(const float* __restrict__ H1,
                                                    const float* __restrict__ att_src,
                                                    const float* __restrict__ att_dst,
                                                    float* __restrict__ a_src,
                                                    float* __restrict__ a_dst) {
    int n = blockIdx.x * 4 + (threadIdx.x >> 6);
    int lane = threadIdx.x & 63;
    float ps[HEADS], pd[HEADS];
#pragma unroll
    for (int h = 0; h < HEADS; ++h) {
        float v = H1[n * D1 + h * 64 + lane];
        ps[h] = v * att_src[h * 64 + lane];
        pd[h] = v * att_dst[h * 64 + lane];
    }
#pragma unroll
    for (int off = 32; off; off >>= 1) {
#pragma unroll
        for (int h = 0; h < HEADS; ++h) {
            ps[h] += __shfl_xor(ps[h], off);
            pd[h] += __shfl_xor(pd[h], off);
        }
    }
    if (lane == 0) {
#pragma unroll
        for (int h = 0; h < HEADS; ++h) {
            a_src[n * HEADS + h] = ps[h];
            a_dst[n * HEADS + h] = pd[h];
        }
    }
}

// ---------------- layer-1 online-softmax aggregation (+bias+ReLU) ----------------

__global__ __launch_bounds__(256) void agg1_kernel(const float* __restrict__ H1,
                                                   const float* __restrict__ a_src,
                                                   const float* __restrict__ a_dst,
                                                   const int* __restrict__ offsets,
                                                   const int* __restrict__ srcIdx,
                                                   const float* __restrict__ b1,
                                                   float* __restrict__ out1) {
    int n = blockIdx.x * 4 + (threadIdx.x >> 6);
    int lane = threadIdx.x & 63;
    float ad[HEADS], m[HEADS], den[HEADS], acc[HEADS];
#pragma unroll
    for (int h = 0; h < HEADS; ++h) {
        ad[h] = a_dst[n * HEADS + h];
        m[h] = -1e30f; den[h] = 0.f; acc[h] = 0.f;
    }
    int beg = offsets[n], end = offsets[n + 1];
    for (int j = beg; j < end; ++j) {
        int s = srcIdx[j];
        const float* hrow = &H1[s * D1];
#pragma unroll
        for (int h = 0; h < HEADS; ++h) {
            float e = a_src[s * HEADS + h] + ad[h];
            e = e > 0.f ? e : NEG_SLOPE * e;
            float nm = fmaxf(m[h], e);
            float sc = __expf(m[h] - nm);
            float p  = __expf(e - nm);
            den[h] = den[h] * sc + p;
            acc[h] = acc[h] * sc + p * hrow[h * 64 + lane];
            m[h] = nm;
        }
    }
#pragma unroll
    for (int h = 0; h < HEADS; ++h) {
        float v = acc[h] / den[h] + b1[h * 64 + lane];
        out1[n * D1 + h * 64 + lane] = fmaxf(v, 0.f);
    }
}

// ---------------- GEMM2 (+ fused a_src2/a_dst2) ----------------

__global__ __launch_bounds__(256) void gemm2_kernel(const float* __restrict__ X,
                                                    const float* __restrict__ W2,
                                                    const float* __restrict__ att_src2,
                                                    const float* __restrict__ att_dst2,
                                                    float* __restrict__ H2,
                                                    float* __restrict__ a_src2,
                                                    float* __restrict__ a_dst2) {
    __shared__ float w2s[D1 * OUT_DIM];   // 48 KB
    __shared__ float xs[8][D1];           // 12 KB
    int t = threadIdx.x;
#pragma unroll
    for (int i = 0; i < 12; ++i) {
        int idx = (i * 256 + t) * 4;
        *reinterpret_cast<float4*>(&w2s[idx]) = *reinterpret_cast<const float4*>(&W2[idx]);
    }
    int n0 = blockIdx.x * 8;
#pragma unroll
    for (int i = 0; i < 3; ++i) {
        int idx = (i * 256 + t) * 4;
        int r = idx / D1, c = idx % D1;
        float4 v = make_float4(0.f, 0.f, 0.f, 0.f);
        if (n0 + r < NN) v = *reinterpret_cast<const float4*>(&X[(n0 + r) * D1 + c]);
        *reinterpret_cast<float4*>(&xs[r][c]) = v;
    }
    __syncthreads();
    int c = t & 31, ln = t >> 5;
    int n = n0 + ln;
    float acc = 0.f;
#pragma unroll 8
    for (int k = 0; k < D1; ++k) acc += xs[ln][k] * w2s[k * OUT_DIM + c];
    float vs = acc * att_src2[c];
    float vd = acc * att_dst2[c];
#pragma unroll
    for (int off = 16; off; off >>= 1) {
        vs += __shfl_xor(vs, off, 32);
        vd += __shfl_xor(vd, off, 32);
    }
    if (n < NN) {
        H2[n * OUT_DIM + c] = acc;
        if (c == 0) { a_src2[n] = vs; a_dst2[n] = vd; }
    }
}

// ---------------- layer-2 aggregation (+b2) -> d_out ----------------

__global__ __launch_bounds__(256) void agg2_kernel(const float* __restrict__ H2,
                                                   const float* __restrict__ a_src,
                                                   const float* __restrict__ a_dst,
                                                   const int* __restrict__ offsets,
                                                   const int* __restrict__ srcIdx,
                                                   const float* __restrict__ b2,
                                                   float* __restrict__ out) {
    int n = blockIdx.x * 4 + (threadIdx.x >> 6);
    int lane = threadIdx.x & 63;
    float ad = a_dst[n];
    float m = -1e30f, den = 0.f, acc = 0.f;
    int beg = offsets[n], end = offsets[n + 1];
    for (int j = beg; j < end; ++j) {
        int s = srcIdx[j];
        float e = a_src[s] + ad;
        e = e > 0.f ? e : NEG_SLOPE * e;
        float nm = fmaxf(m, e);
        float sc = __expf(m - nm);
        float p  = __expf(e - nm);
        den = den * sc + p;
        if (lane < 32) acc = acc * sc + p * H2[s * OUT_DIM + lane];
        m = nm;
    }
    if (lane < 32) out[n * OUT_DIM + lane] = acc / den + b2[lane];
}

// ---------------- launch ----------------

static inline size_t align256(size_t x) { return (x + 255) & ~size_t(255); }

extern "C" void kernel_launch(void* const* d_in, const int* in_sizes, int n_in,
                              void* d_out, int out_size, void* d_ws, size_t ws_size,
                              hipStream_t stream) {
    const float* x        = (const float*)d_in[0];
    const int*   ei       = (const int*)d_in[1];     // [2,E]: src then dst
    const float* W1       = (const float*)d_in[2];
    const float* att_src1 = (const float*)d_in[3];
    const float* att_dst1 = (const float*)d_in[4];
    const float* b1       = (const float*)d_in[5];
    const float* W2       = (const float*)d_in[6];
    const float* att_src2 = (const float*)d_in[7];
    const float* att_dst2 = (const float*)d_in[8];
    const float* b2       = (const float*)d_in[9];
    float* out = (float*)d_out;

    const int* e_src = ei;
    const int* e_dst = ei + EE;

    char* p = (char*)d_ws;
    float* H1   = (float*)p; p += align256(sizeof(float) * NN * D1);
    float* OUT1 = (float*)p; p += align256(sizeof(float) * NN * D1);
    float* H2   = (float*)p; p += align256(sizeof(float) * NN * OUT_DIM);
    float* AS1  = (float*)p; p += align256(sizeof(float) * NN * HEADS);
    float* AD1  = (float*)p; p += align256(sizeof(float) * NN * HEADS);
    float* AS2  = (float*)p; p += align256(sizeof(float) * NN);
    float* AD2  = (float*)p; p += align256(sizeof(float) * NN);
    int*   DEG  = (int*)p;   p += align256(sizeof(int) * NN);
    int*   OFF  = (int*)p;   p += align256(sizeof(int) * (NN + 1));
    int*   CUR  = (int*)p;   p += align256(sizeof(int) * NN);
    int*   SIDX = (int*)p;   p += align256(sizeof(int) * (EE + NN));

    // CSR build
    deg_init_kernel<<<(NN + 255) / 256, 256, 0, stream>>>(DEG);
    hist_kernel<<<(EE + 255) / 256, 256, 0, stream>>>(e_dst, DEG);
    scan_kernel<<<1, 1024, 0, stream>>>(DEG, OFF, CUR);
    scatter_kernel<<<(EE + NN + 255) / 256, 256, 0, stream>>>(e_src, e_dst, CUR, SIDX);

    // layer 1
    gemm1_kernel<<<dim3(D1 / 64, (NN + 63) / 64), 256, 0, stream>>>(x, W1, H1);
    avec1_kernel<<<NN / 4, 256, 0, stream>>>(H1, att_src1, att_dst1, AS1, AD1);
    agg1_kernel<<<NN / 4, 256, 0, stream>>>(H1, AS1, AD1, OFF, SIDX, b1, OUT1);

    // layer 2
    gemm2_kernel<<<NN / 8, 256, 0, stream>>>(OUT1, W2, att_src2, att_dst2, H2, AS2, AD2);
    agg2_kernel<<<NN / 4, 256, 0, stream>>>(H2, AS2, AD2, OFF, SIDX, b2, out);
}

// Round 2
// 513.187 us; speedup vs baseline: 1.4766x; 1.4766x over previous
//
#include <hip/hip_runtime.h>
#include <hip/hip_bf16.h>

#define NN 50000
#define EE 800000
#define IN_DIM 256
#define HID 64
#define HEADS 6
#define D1 384            // HEADS*HID
#define OUT_DIM 32
#define NEG_SLOPE 0.2f
#define CAP 128           // edge chunk per node held in LDS

typedef unsigned int uint32;
typedef unsigned short ushort_t;
typedef short short8 __attribute__((ext_vector_type(8)));
typedef float f32x4 __attribute__((ext_vector_type(4)));
typedef ushort_t ushort8 __attribute__((ext_vector_type(8)));
typedef ushort_t ushort4v __attribute__((ext_vector_type(4)));

__device__ __forceinline__ ushort_t f2bf(float f) {
    uint32 u = __builtin_bit_cast(uint32, f);
    u += 0x7fffu + ((u >> 16) & 1u);
    return (ushort_t)(u >> 16);
}
__device__ __forceinline__ float bf2f(ushort_t s) {
    uint32 u = ((uint32)s) << 16;
    return __builtin_bit_cast(float, u);
}

// ---------------- CSR build ----------------

__global__ void deg_init_kernel(int* __restrict__ deg) {
    int i = blockIdx.x * 256 + threadIdx.x;
    if (i < NN) deg[i] = 1;   // self-loop
}

__global__ void hist_kernel(const int* __restrict__ dst, int* __restrict__ deg) {
    int i = blockIdx.x * 256 + threadIdx.x;
    if (i < EE) atomicAdd(&deg[dst[i]], 1);
}

__global__ __launch_bounds__(1024) void scan_kernel(const int* __restrict__ deg,
                                                    int* __restrict__ offsets,
                                                    int* __restrict__ cursor) {
    __shared__ int part[1024];
    int t = threadIdx.x;
    const int CH = 49;  // ceil(50000/1024)
    int lo = t * CH;
    int hi = lo + CH; if (hi > NN) hi = NN; if (lo > NN) lo = NN;
    int s = 0;
    for (int i = lo; i < hi; ++i) s += deg[i];
    part[t] = s;
    __syncthreads();
    for (int off = 1; off < 1024; off <<= 1) {
        int v = (t >= off) ? part[t - off] : 0;
        __syncthreads();
        part[t] += v;
        __syncthreads();
    }
    int run = (t == 0) ? 0 : part[t - 1];
    for (int i = lo; i < hi; ++i) {
        offsets[i] = run; cursor[i] = run;
        run += deg[i];
    }
    if (t == 1023) offsets[NN] = run;  // == EE+NN
}

__global__ void scatter_kernel(const int* __restrict__ src, const int* __restrict__ dst,
                               int* __restrict__ cursor, int* __restrict__ srcIdx) {
    int i = blockIdx.x * 256 + threadIdx.x;
    if (i >= EE + NN) return;
    int s, d;
    if (i < EE) { s = src[i]; d = dst[i]; }
    else        { s = i - EE; d = s; }
    int pos = atomicAdd(&cursor[d], 1);
    srcIdx[pos] = s;
}

// ---------------- W1 transpose + bf16 convert: [256][384] -> [384][256] bf16 ----------------

__global__ __launch_bounds__(256) void w1t_kernel(const float* __restrict__ W1,
                                                  ushort_t* __restrict__ W1Tb) {
    __shared__ float tile[32][33];
    int tx = threadIdx.x & 31, ty = threadIdx.x >> 5;   // 32x8
    int n0 = blockIdx.x * 32;  // n in 0..383
    int k0 = blockIdx.y * 32;  // k in 0..255
#pragma unroll
    for (int i = 0; i < 4; ++i)
        tile[ty + i * 8][tx] = W1[(k0 + ty + i * 8) * D1 + n0 + tx];
    __syncthreads();
#pragma unroll
    for (int i = 0; i < 4; ++i)
        W1Tb[(n0 + ty + i * 8) * IN_DIM + k0 + tx] = f2bf(tile[tx][ty + i * 8]);
}

// ---------------- GEMM1: H1b = bf16( x @ W1 )  via MFMA ----------------
// block tile: 64 rows x 384 cols (full N), K=256 in 4 steps of 64.
// 4 waves; wave w covers cols w*96 .. +96 (6 frags of 16), all 64 rows (4 frags).

#define G1_BM 64
#define G1_BK 64

__global__ __launch_bounds__(256) void gemm1_kernel(const float* __restrict__ A,
                                                    const ushort_t* __restrict__ Bt,
                                                    ushort_t* __restrict__ Cb) {
    __shared__ __align__(16) ushort_t As[G1_BM][G1_BK];   // 8 KB, 16B-chunk XOR swizzle
    __shared__ __align__(16) ushort_t Bs[D1][G1_BK];      // 48 KB, same swizzle
    int t = threadIdx.x;
    int m0 = blockIdx.x * G1_BM;
    int wid = t >> 6, lane = t & 63;
    int lrow = lane & 15, lk = lane >> 4;
    f32x4 acc[4][6] = {};
    for (int k0 = 0; k0 < IN_DIM; k0 += G1_BK) {
        // stage A (f32 -> bf16): 64 rows x 8 chunks(16B)
        {
            int r = t >> 3, c = t & 7;
#pragma unroll
            for (int p = 0; p < 2; ++p) {
                int row = p * 32 + r;
                int gr = m0 + row;
                float4 v0 = make_float4(0.f, 0.f, 0.f, 0.f), v1 = v0;
                if (gr < NN) {
                    const float* g = &A[(size_t)gr * IN_DIM + k0 + c * 8];
                    v0 = *reinterpret_cast<const float4*>(g);
                    v1 = *reinterpret_cast<const float4*>(g + 4);
                }
                ushort8 u;
                u[0] = f2bf(v0.x); u[1] = f2bf(v0.y); u[2] = f2bf(v0.z); u[3] = f2bf(v0.w);
                u[4] = f2bf(v1.x); u[5] = f2bf(v1.y); u[6] = f2bf(v1.z); u[7] = f2bf(v1.w);
                *reinterpret_cast<ushort8*>(&As[row][(c ^ (row & 7)) * 8]) = u;
            }
        }
        // stage B (already bf16): 384 rows x 8 chunks
        {
            int r = t >> 3, c = t & 7;
#pragma unroll
            for (int p = 0; p < 12; ++p) {
                int row = p * 32 + r;
                ushort8 u = *reinterpret_cast<const ushort8*>(&Bt[row * IN_DIM + k0 + c * 8]);
                *reinterpret_cast<ushort8*>(&Bs[row][(c ^ (row & 7)) * 8]) = u;
            }
        }
        __syncthreads();
#pragma unroll
        for (int kk = 0; kk < G1_BK; kk += 32) {
            int ckb = (kk >> 3) + lk;
            short8 af[4];
#pragma unroll
            for (int fm = 0; fm < 4; ++fm) {
                int m = fm * 16 + lrow;
                af[fm] = *reinterpret_cast<const short8*>(&As[m][(ckb ^ (m & 7)) * 8]);
            }
#pragma unroll
            for (int fn = 0; fn < 6; ++fn) {
                int n = wid * 96 + fn * 16 + lrow;
                short8 bfv = *reinterpret_cast<const short8*>(&Bs[n][(ckb ^ (n & 7)) * 8]);
#pragma unroll
                for (int fm = 0; fm < 4; ++fm)
                    acc[fm][fn] = __builtin_amdgcn_mfma_f32_16x16x32_bf16(af[fm], bfv, acc[fm][fn], 0, 0, 0);
            }
        }
        __syncthreads();
    }
    // epilogue: C/D layout col = lane&15, row = (lane>>4)*4 + reg
#pragma unroll
    for (int fm = 0; fm < 4; ++fm) {
#pragma unroll
        for (int r = 0; r < 4; ++r) {
            int row = m0 + fm * 16 + lk * 4 + r;
            if (row < NN) {
#pragma unroll
                for (int fn = 0; fn < 6; ++fn) {
                    int col = wid * 96 + fn * 16 + lrow;
                    Cb[(size_t)row * D1 + col] = f2bf(acc[fm][fn][r]);
                }
            }
        }
    }
}

// ---------------- per-node attention coefficients, layer 1 ----------------

__global__ __launch_bounds__(256) void avec1_kernel(const ushort_t* __restrict__ H1b,
                                                    const float* __restrict__ att_src,
                                                    const float* __restrict__ att_dst,
                                                    float* __restrict__ a_src,
                                                    float* __restrict__ a_dst) {
    int n = blockIdx.x * 4 + (threadIdx.x >> 6);
    int lane = threadIdx.x & 63;
    float ps[HEADS], pd[HEADS];
#pragma unroll
    for (int h = 0; h < HEADS; ++h) {
        float v = bf2f(H1b[(size_t)n * D1 + h * 64 + lane]);
        ps[h] = v * att_src[h * 64 + lane];
        pd[h] = v * att_dst[h * 64 + lane];
    }
#pragma unroll
    for (int off = 32; off; off >>= 1) {
#pragma unroll
        for (int h = 0; h < HEADS; ++h) {
            ps[h] += __shfl_xor(ps[h], off);
            pd[h] += __shfl_xor(pd[h], off);
        }
    }
    if (lane == 0) {
#pragma unroll
        for (int h = 0; h < HEADS; ++h) {
            a_src[n * HEADS + h] = ps[h];
            a_dst[n * HEADS + h] = pd[h];
        }
    }
}

// ---------------- layer-1 aggregation: two-phase chunked online softmax ----------------

__global__ __launch_bounds__(256) void agg1_kernel(const ushort_t* __restrict__ H1b,
                                                   const float* __restrict__ a_src,
                                                   const float* __restrict__ a_dst,
                                                   const int* __restrict__ offsets,
                                                   const int* __restrict__ srcIdx,
                                                   const float* __restrict__ b1,
                                                   ushort_t* __restrict__ out1b) {
    __shared__ float pl[4][CAP][HEADS];   // 12 KB
    __shared__ int   sl[4][CAP];          // 2 KB
    int w = threadIdx.x >> 6, lane = threadIdx.x & 63;
    int n = blockIdx.x * 4 + w;
    float ad[HEADS], m[HEADS], den[HEADS], acc[HEADS];
#pragma unroll
    for (int h = 0; h < HEADS; ++h) {
        ad[h] = a_dst[n * HEADS + h];
        m[h] = -1e30f; den[h] = 0.f; acc[h] = 0.f;
    }
    int beg = offsets[n], end = offsets[n + 1];
    for (int cbeg = beg; cbeg < end; cbeg += CAP) {
        int L = end - cbeg; if (L > CAP) L = CAP;
        // ---- phase A: lanes over edges ----
        float emax[HEADS];
#pragma unroll
        for (int h = 0; h < HEADS; ++h) emax[h] = -1e30f;
        for (int tI = lane; tI < L; tI += 64) {
            int s = srcIdx[cbeg + tI];
            sl[w][tI] = s;
#pragma unroll
            for (int h = 0; h < HEADS; ++h) {
                float e = a_src[s * HEADS + h] + ad[h];
                e = e > 0.f ? e : NEG_SLOPE * e;
                pl[w][tI][h] = e;
                emax[h] = fmaxf(emax[h], e);
            }
        }
        float nm[HEADS], sc[HEADS];
#pragma unroll
        for (int h = 0; h < HEADS; ++h) {
            float wm = emax[h];
#pragma unroll
            for (int o = 32; o; o >>= 1) wm = fmaxf(wm, __shfl_xor(wm, o));
            nm[h] = fmaxf(m[h], wm);
            sc[h] = __expf(m[h] - nm[h]);
        }
        float lden[HEADS] = {0.f, 0.f, 0.f, 0.f, 0.f, 0.f};
        for (int tI = lane; tI < L; tI += 64) {
#pragma unroll
            for (int h = 0; h < HEADS; ++h) {
                float p = __expf(pl[w][tI][h] - nm[h]);
                pl[w][tI][h] = p;
                lden[h] += p;
            }
        }
#pragma unroll
        for (int h = 0; h < HEADS; ++h) {
            float wd = lden[h];
#pragma unroll
            for (int o = 32; o; o >>= 1) wd += __shfl_xor(wd, o);
            den[h] = den[h] * sc[h] + wd;
            acc[h] *= sc[h];
            m[h] = nm[h];
        }
        // ---- phase B: lanes over channels ----
#pragma unroll 2
        for (int j = 0; j < L; ++j) {
            int s = sl[w][j];
            const ushort_t* hr = &H1b[(size_t)s * D1 + lane];
#pragma unroll
            for (int h = 0; h < HEADS; ++h)
                acc[h] += pl[w][j][h] * bf2f(hr[h * 64]);
        }
    }
#pragma unroll
    for (int h = 0; h < HEADS; ++h) {
        float v = acc[h] / den[h] + b1[h * 64 + lane];
        out1b[(size_t)n * D1 + h * 64 + lane] = f2bf(fmaxf(v, 0.f));
    }
}

// ---------------- GEMM2 (+ fused a_src2/a_dst2), bf16 in, bf16 feature out ----------------

__global__ __launch_bounds__(256) void gemm2_kernel(const ushort_t* __restrict__ Xb,
                                                    const float* __restrict__ W2,
                                                    const float* __restrict__ att_src2,
                                                    const float* __restrict__ att_dst2,
                                                    ushort_t* __restrict__ H2b,
                                                    float* __restrict__ a_src2,
                                                    float* __restrict__ a_dst2) {
    __shared__ float w2s[D1 * OUT_DIM];   // 48 KB
    __shared__ float xs[8][D1];           // 12 KB
    int t = threadIdx.x;
#pragma unroll
    for (int i = 0; i < 12; ++i) {
        int idx = (i * 256 + t) * 4;
        *reinterpret_cast<float4*>(&w2s[idx]) = *reinterpret_cast<const float4*>(&W2[idx]);
    }
    int n0 = blockIdx.x * 8;
#pragma unroll
    for (int i = 0; i < 3; ++i) {
        int idx4 = i * 256 + t;
        int r = idx4 / 96, c4 = (idx4 % 96) * 4;
        float4 v = make_float4(0.f, 0.f, 0.f, 0.f);
        if (n0 + r < NN) {
            ushort4v u = *reinterpret_cast<const ushort4v*>(&Xb[(size_t)(n0 + r) * D1 + c4]);
            v = make_float4(bf2f(u[0]), bf2f(u[1]), bf2f(u[2]), bf2f(u[3]));
        }
        *reinterpret_cast<float4*>(&xs[r][c4]) = v;
    }
    __syncthreads();
    int c = t & 31, ln = t >> 5;
    int n = n0 + ln;
    float acc = 0.f;
#pragma unroll 8
    for (int k = 0; k < D1; ++k) acc += xs[ln][k] * w2s[k * OUT_DIM + c];
    float vs = acc * att_src2[c];
    float vd = acc * att_dst2[c];
#pragma unroll
    for (int off = 16; off; off >>= 1) {
        vs += __shfl_xor(vs, off, 32);
        vd += __shfl_xor(vd, off, 32);
    }
    if (n < NN) {
        H2b[(size_t)n * OUT_DIM + c] = f2bf(acc);
        if (c == 0) { a_src2[n] = vs; a_dst2[n] = vd; }
    }
}

// ---------------- layer-2 aggregation (+b2) -> d_out ----------------

__global__ __launch_bounds__(256) void agg2_kernel(const ushort_t* __restrict__ H2b,
                                                   const float* __restrict__ a_src,
                                                   const float* __restrict__ a_dst,
                                                   const int* __restrict__ offsets,
                                                   const int* __restrict__ srcIdx,
                                                   const float* __restrict__ b2,
                                                   float* __restrict__ out) {
    __shared__ float pl[4][CAP];
    __shared__ int   sl[4][CAP];
    int w = threadIdx.x >> 6, lane = threadIdx.x & 63;
    int n = blockIdx.x * 4 + w;
    int c = lane & 31, par = lane >> 5;
    float ad = a_dst[n];
    float m = -1e30f, den = 0.f, acc = 0.f;
    int beg = offsets[n], end = offsets[n + 1];
    for (int cbeg = beg; cbeg < end; cbeg += CAP) {
        int L = end - cbeg; if (L > CAP) L = CAP;
        float emax = -1e30f;
        for (int tI = lane; tI < L; tI += 64) {
            int s = srcIdx[cbeg + tI];
            sl[w][tI] = s;
            float e = a_src[s] + ad;
            e = e > 0.f ? e : NEG_SLOPE * e;
            pl[w][tI] = e;
            emax = fmaxf(emax, e);
        }
        float wm = emax;
#pragma unroll
        for (int o = 32; o; o >>= 1) wm = fmaxf(wm, __shfl_xor(wm, o));
        float nm = fmaxf(m, wm);
        float sc = __expf(m - nm);
        float lden = 0.f;
        for (int tI = lane; tI < L; tI += 64) {
            float p = __expf(pl[w][tI] - nm);
            pl[w][tI] = p;
            lden += p;
        }
        float wd = lden;
#pragma unroll
        for (int o = 32; o; o >>= 1) wd += __shfl_xor(wd, o);
        den = den * sc + wd;
        acc *= sc;
        m = nm;
        for (int j = par; j < L; j += 2)
            acc += pl[w][j] * bf2f(H2b[(size_t)sl[w][j] * OUT_DIM + c]);
    }
    acc += __shfl_xor(acc, 32);
    if (lane < 32) out[(size_t)n * OUT_DIM + c] = acc / den + b2[c];
}

// ---------------- launch ----------------

static inline size_t align256(size_t x) { return (x + 255) & ~size_t(255); }

extern "C" void kernel_launch(void* const* d_in, const int* in_sizes, int n_in,
                              void* d_out, int out_size, void* d_ws, size_t ws_size,
                              hipStream_t stream) {
    const float* x        = (const float*)d_in[0];
    const int*   ei       = (const int*)d_in[1];
    const float* W1       = (const float*)d_in[2];
    const float* att_src1 = (const float*)d_in[3];
    const float* att_dst1 = (const float*)d_in[4];
    const float* b1       = (const float*)d_in[5];
    const float* W2       = (const float*)d_in[6];
    const float* att_src2 = (const float*)d_in[7];
    const float* att_dst2 = (const float*)d_in[8];
    const float* b2       = (const float*)d_in[9];
    float* out = (float*)d_out;

    const int* e_src = ei;
    const int* e_dst = ei + EE;

    char* p = (char*)d_ws;
    ushort_t* H1b   = (ushort_t*)p; p += align256(sizeof(ushort_t) * (size_t)NN * D1);
    ushort_t* OUT1b = (ushort_t*)p; p += align256(sizeof(ushort_t) * (size_t)NN * D1);
    ushort_t* H2b   = (ushort_t*)p; p += align256(sizeof(ushort_t) * (size_t)NN * OUT_DIM);
    ushort_t* W1Tb  = (ushort_t*)p; p += align256(sizeof(ushort_t) * D1 * IN_DIM);
    float* AS1  = (float*)p; p += align256(sizeof(float) * NN * HEADS);
    float* AD1  = (float*)p; p += align256(sizeof(float) * NN * HEADS);
    float* AS2  = (float*)p; p += align256(sizeof(float) * NN);
    float* AD2  = (float*)p; p += align256(sizeof(float) * NN);
    int*   DEG  = (int*)p;   p += align256(sizeof(int) * NN);
    int*   OFF  = (int*)p;   p += align256(sizeof(int) * (NN + 1));
    int*   CUR  = (int*)p;   p += align256(sizeof(int) * NN);
    int*   SIDX = (int*)p;   p += align256(sizeof(int) * (EE + NN));

    // CSR build + weight prep
    w1t_kernel<<<dim3(D1 / 32, IN_DIM / 32), 256, 0, stream>>>(W1, W1Tb);
    deg_init_kernel<<<(NN + 255) / 256, 256, 0, stream>>>(DEG);
    hist_kernel<<<(EE + 255) / 256, 256, 0, stream>>>(e_dst, DEG);
    scan_kernel<<<1, 1024, 0, stream>>>(DEG, OFF, CUR);
    scatter_kernel<<<(EE + NN + 255) / 256, 256, 0, stream>>>(e_src, e_dst, CUR, SIDX);

    // layer 1
    gemm1_kernel<<<(NN + G1_BM - 1) / G1_BM, 256, 0, stream>>>(x, W1Tb, H1b);
    avec1_kernel<<<NN / 4, 256, 0, stream>>>(H1b, att_src1, att_dst1, AS1, AD1);
    agg1_kernel<<<NN / 4, 256, 0, stream>>>(H1b, AS1, AD1, OFF, SIDX, b1, OUT1b);

    // layer 2
    gemm2_kernel<<<NN / 8, 256, 0, stream>>>(OUT1b, W2, att_src2, att_dst2, H2b, AS2, AD2);
    agg2_kernel<<<NN / 4, 256, 0, stream>>>(H2b, AS2, AD2, OFF, SIDX, b2, out);
}

// Round 3
// 408.511 us; speedup vs baseline: 1.8550x; 1.2562x over previous
//
#include <hip/hip_runtime.h>
#include <hip/hip_bf16.h>

#define NN 50000
#define EE 800000
#define IN_DIM 256
#define HID 64
#define HEADS 6
#define D1 384            // HEADS*HID
#define OUT_DIM 32
#define NEG_SLOPE 0.2f
#define CAP 128           // edge chunk per node held in LDS
#define NBLK 196          // ceil(50000/256)

typedef unsigned int uint32;
typedef unsigned short ushort_t;
typedef short short8 __attribute__((ext_vector_type(8)));
typedef float f32x4 __attribute__((ext_vector_type(4)));
typedef ushort_t ushort8 __attribute__((ext_vector_type(8)));
typedef ushort_t ushort4v __attribute__((ext_vector_type(4)));

__device__ __forceinline__ ushort_t f2bf(float f) {
    uint32 u = __builtin_bit_cast(uint32, f);
    u += 0x7fffu + ((u >> 16) & 1u);
    return (ushort_t)(u >> 16);
}
__device__ __forceinline__ float bf2f(ushort_t s) {
    uint32 u = ((uint32)s) << 16;
    return __builtin_bit_cast(float, u);
}

// ---------------- CSR build ----------------

__global__ void deg_init_kernel(int* __restrict__ deg) {
    int i = blockIdx.x * 256 + threadIdx.x;
    if (i < NN) deg[i] = 1;   // self-loop
}

__global__ void hist_kernel(const int* __restrict__ dst, int* __restrict__ deg) {
    int i = blockIdx.x * 256 + threadIdx.x;
    if (i < EE) atomicAdd(&deg[dst[i]], 1);
}

// hierarchical scan: (1) per-block sums
__global__ __launch_bounds__(256) void scan1_kernel(const int* __restrict__ deg,
                                                    int* __restrict__ blockSums) {
    int t = threadIdx.x;
    int i = blockIdx.x * 256 + t;
    int v = (i < NN) ? deg[i] : 0;
#pragma unroll
    for (int o = 32; o; o >>= 1) v += __shfl_xor(v, o);
    __shared__ int ws[4];
    if ((t & 63) == 0) ws[t >> 6] = v;
    __syncthreads();
    if (t == 0) blockSums[blockIdx.x] = ws[0] + ws[1] + ws[2] + ws[3];
}

// (2) single small block scans NBLK partials -> exclusive block prefixes
__global__ __launch_bounds__(256) void scan2_kernel(const int* __restrict__ blockSums,
                                                    int* __restrict__ blockPrefix,
                                                    int* __restrict__ offsets) {
    int t = threadIdx.x;
    int lane = t & 63, w = t >> 6;
    int v = (t < NBLK) ? blockSums[t] : 0;
    int x = v;
#pragma unroll
    for (int o = 1; o < 64; o <<= 1) {
        int y = __shfl_up(x, o);
        if (lane >= o) x += y;
    }
    __shared__ int ws[4];
    if (lane == 63) ws[w] = x;
    __syncthreads();
    int wpre = 0;
#pragma unroll
    for (int k = 0; k < 4; ++k) if (k < w) wpre += ws[k];
    int incl = x + wpre;
    if (t < NBLK) blockPrefix[t] = incl - v;
    if (t == NBLK - 1) offsets[NN] = incl;   // total == EE+NN
}

// (3) per-block exclusive scan + block prefix -> offsets & cursor
__global__ __launch_bounds__(256) void scan3_kernel(const int* __restrict__ deg,
                                                    const int* __restrict__ blockPrefix,
                                                    int* __restrict__ offsets,
                                                    int* __restrict__ cursor) {
    int t = threadIdx.x;
    int i = blockIdx.x * 256 + t;
    int lane = t & 63, w = t >> 6;
    int v = (i < NN) ? deg[i] : 0;
    int x = v;
#pragma unroll
    for (int o = 1; o < 64; o <<= 1) {
        int y = __shfl_up(x, o);
        if (lane >= o) x += y;
    }
    __shared__ int ws[4];
    if (lane == 63) ws[w] = x;
    __syncthreads();
    int wpre = 0;
#pragma unroll
    for (int k = 0; k < 4; ++k) if (k < w) wpre += ws[k];
    int excl = x + wpre - v + blockPrefix[blockIdx.x];
    if (i < NN) { offsets[i] = excl; cursor[i] = excl; }
}

__global__ void scatter_kernel(const int* __restrict__ src, const int* __restrict__ dst,
                               int* __restrict__ cursor, int* __restrict__ srcIdx) {
    int i = blockIdx.x * 256 + threadIdx.x;
    if (i >= EE + NN) return;
    int s, d;
    if (i < EE) { s = src[i]; d = dst[i]; }
    else        { s = i - EE; d = s; }
    int pos = atomicAdd(&cursor[d], 1);
    srcIdx[pos] = s;
}

// ---------------- W1 transpose + bf16 convert: [256][384] -> [384][256] bf16 ----------------

__global__ __launch_bounds__(256) void w1t_kernel(const float* __restrict__ W1,
                                                  ushort_t* __restrict__ W1Tb) {
    __shared__ float tile[32][33];
    int tx = threadIdx.x & 31, ty = threadIdx.x >> 5;   // 32x8
    int n0 = blockIdx.x * 32;  // n in 0..383
    int k0 = blockIdx.y * 32;  // k in 0..255
#pragma unroll
    for (int i = 0; i < 4; ++i)
        tile[ty + i * 8][tx] = W1[(k0 + ty + i * 8) * D1 + n0 + tx];
    __syncthreads();
#pragma unroll
    for (int i = 0; i < 4; ++i)
        W1Tb[(n0 + ty + i * 8) * IN_DIM + k0 + tx] = f2bf(tile[tx][ty + i * 8]);
}

// ---------------- GEMM1: H1b = bf16( x @ W1 )  via MFMA ----------------

#define G1_BM 64
#define G1_BK 64

__global__ __launch_bounds__(256) void gemm1_kernel(const float* __restrict__ A,
                                                    const ushort_t* __restrict__ Bt,
                                                    ushort_t* __restrict__ Cb) {
    __shared__ __align__(16) ushort_t As[G1_BM][G1_BK];   // 8 KB, 16B-chunk XOR swizzle
    __shared__ __align__(16) ushort_t Bs[D1][G1_BK];      // 48 KB, same swizzle
    int t = threadIdx.x;
    int m0 = blockIdx.x * G1_BM;
    int wid = t >> 6, lane = t & 63;
    int lrow = lane & 15, lk = lane >> 4;
    f32x4 acc[4][6] = {};
    for (int k0 = 0; k0 < IN_DIM; k0 += G1_BK) {
        {
            int r = t >> 3, c = t & 7;
#pragma unroll
            for (int p = 0; p < 2; ++p) {
                int row = p * 32 + r;
                int gr = m0 + row;
                float4 v0 = make_float4(0.f, 0.f, 0.f, 0.f), v1 = v0;
                if (gr < NN) {
                    const float* g = &A[(size_t)gr * IN_DIM + k0 + c * 8];
                    v0 = *reinterpret_cast<const float4*>(g);
                    v1 = *reinterpret_cast<const float4*>(g + 4);
                }
                ushort8 u;
                u[0] = f2bf(v0.x); u[1] = f2bf(v0.y); u[2] = f2bf(v0.z); u[3] = f2bf(v0.w);
                u[4] = f2bf(v1.x); u[5] = f2bf(v1.y); u[6] = f2bf(v1.z); u[7] = f2bf(v1.w);
                *reinterpret_cast<ushort8*>(&As[row][(c ^ (row & 7)) * 8]) = u;
            }
        }
        {
            int r = t >> 3, c = t & 7;
#pragma unroll
            for (int p = 0; p < 12; ++p) {
                int row = p * 32 + r;
                ushort8 u = *reinterpret_cast<const ushort8*>(&Bt[row * IN_DIM + k0 + c * 8]);
                *reinterpret_cast<ushort8*>(&Bs[row][(c ^ (row & 7)) * 8]) = u;
            }
        }
        __syncthreads();
#pragma unroll
        for (int kk = 0; kk < G1_BK; kk += 32) {
            int ckb = (kk >> 3) + lk;
            short8 af[4];
#pragma unroll
            for (int fm = 0; fm < 4; ++fm) {
                int m = fm * 16 + lrow;
                af[fm] = *reinterpret_cast<const short8*>(&As[m][(ckb ^ (m & 7)) * 8]);
            }
#pragma unroll
            for (int fn = 0; fn < 6; ++fn) {
                int n = wid * 96 + fn * 16 + lrow;
                short8 bfv = *reinterpret_cast<const short8*>(&Bs[n][(ckb ^ (n & 7)) * 8]);
#pragma unroll
                for (int fm = 0; fm < 4; ++fm)
                    acc[fm][fn] = __builtin_amdgcn_mfma_f32_16x16x32_bf16(af[fm], bfv, acc[fm][fn], 0, 0, 0);
            }
        }
        __syncthreads();
    }
#pragma unroll
    for (int fm = 0; fm < 4; ++fm) {
#pragma unroll
        for (int r = 0; r < 4; ++r) {
            int row = m0 + fm * 16 + lk * 4 + r;
            if (row < NN) {
#pragma unroll
                for (int fn = 0; fn < 6; ++fn) {
                    int col = wid * 96 + fn * 16 + lrow;
                    Cb[(size_t)row * D1 + col] = f2bf(acc[fm][fn][r]);
                }
            }
        }
    }
}

// ---------------- per-node attention coefficients, layer 1 ----------------

__global__ __launch_bounds__(256) void avec1_kernel(const ushort_t* __restrict__ H1b,
                                                    const float* __restrict__ att_src,
                                                    const float* __restrict__ att_dst,
                                                    float* __restrict__ a_src,
                                                    float* __restrict__ a_dst) {
    int n = blockIdx.x * 4 + (threadIdx.x >> 6);
    int lane = threadIdx.x & 63;
    float ps[HEADS], pd[HEADS];
#pragma unroll
    for (int h = 0; h < HEADS; ++h) {
        float v = bf2f(H1b[(size_t)n * D1 + h * 64 + lane]);
        ps[h] = v * att_src[h * 64 + lane];
        pd[h] = v * att_dst[h * 64 + lane];
    }
#pragma unroll
    for (int off = 32; off; off >>= 1) {
#pragma unroll
        for (int h = 0; h < HEADS; ++h) {
            ps[h] += __shfl_xor(ps[h], off);
            pd[h] += __shfl_xor(pd[h], off);
        }
    }
    if (lane == 0) {
#pragma unroll
        for (int h = 0; h < HEADS; ++h) {
            a_src[n * HEADS + h] = ps[h];
            a_dst[n * HEADS + h] = pd[h];
        }
    }
}

// ---------------- layer-1 aggregation: two-phase chunked online softmax ----------------

__global__ __launch_bounds__(256) void agg1_kernel(const ushort_t* __restrict__ H1b,
                                                   const float* __restrict__ a_src,
                                                   const float* __restrict__ a_dst,
                                                   const int* __restrict__ offsets,
                                                   const int* __restrict__ srcIdx,
                                                   const float* __restrict__ b1,
                                                   ushort_t* __restrict__ out1b) {
    __shared__ float pl[4][CAP][HEADS];   // 12 KB
    __shared__ int   sl[4][CAP];          // 2 KB
    int w = threadIdx.x >> 6, lane = threadIdx.x & 63;
    int n = blockIdx.x * 4 + w;
    float ad[HEADS], m[HEADS], den[HEADS], acc[HEADS];
#pragma unroll
    for (int h = 0; h < HEADS; ++h) {
        ad[h] = a_dst[n * HEADS + h];
        m[h] = -1e30f; den[h] = 0.f; acc[h] = 0.f;
    }
    int beg = offsets[n], end = offsets[n + 1];
    for (int cbeg = beg; cbeg < end; cbeg += CAP) {
        int L = end - cbeg; if (L > CAP) L = CAP;
        float emax[HEADS];
#pragma unroll
        for (int h = 0; h < HEADS; ++h) emax[h] = -1e30f;
        for (int tI = lane; tI < L; tI += 64) {
            int s = srcIdx[cbeg + tI];
            sl[w][tI] = s;
#pragma unroll
            for (int h = 0; h < HEADS; ++h) {
                float e = a_src[s * HEADS + h] + ad[h];
                e = e > 0.f ? e : NEG_SLOPE * e;
                pl[w][tI][h] = e;
                emax[h] = fmaxf(emax[h], e);
            }
        }
        float nm[HEADS], sc[HEADS];
#pragma unroll
        for (int h = 0; h < HEADS; ++h) {
            float wm = emax[h];
#pragma unroll
            for (int o = 32; o; o >>= 1) wm = fmaxf(wm, __shfl_xor(wm, o));
            nm[h] = fmaxf(m[h], wm);
            sc[h] = __expf(m[h] - nm[h]);
        }
        float lden[HEADS] = {0.f, 0.f, 0.f, 0.f, 0.f, 0.f};
        for (int tI = lane; tI < L; tI += 64) {
#pragma unroll
            for (int h = 0; h < HEADS; ++h) {
                float p = __expf(pl[w][tI][h] - nm[h]);
                pl[w][tI][h] = p;
                lden[h] += p;
            }
        }
#pragma unroll
        for (int h = 0; h < HEADS; ++h) {
            float wd = lden[h];
#pragma unroll
            for (int o = 32; o; o >>= 1) wd += __shfl_xor(wd, o);
            den[h] = den[h] * sc[h] + wd;
            acc[h] *= sc[h];
            m[h] = nm[h];
        }
#pragma unroll 2
        for (int j = 0; j < L; ++j) {
            int s = sl[w][j];
            const ushort_t* hr = &H1b[(size_t)s * D1 + lane];
#pragma unroll
            for (int h = 0; h < HEADS; ++h)
                acc[h] += pl[w][j][h] * bf2f(hr[h * 64]);
        }
    }
#pragma unroll
    for (int h = 0; h < HEADS; ++h) {
        float v = acc[h] / den[h] + b1[h * 64 + lane];
        out1b[(size_t)n * D1 + h * 64 + lane] = f2bf(fmaxf(v, 0.f));
    }
}

// ---------------- GEMM2 (+ fused a_src2/a_dst2), bf16 in, bf16 feature out ----------------

__global__ __launch_bounds__(256) void gemm2_kernel(const ushort_t* __restrict__ Xb,
                                                    const float* __restrict__ W2,
                                                    const float* __restrict__ att_src2,
                                                    const float* __restrict__ att_dst2,
                                                    ushort_t* __restrict__ H2b,
                                                    float* __restrict__ a_src2,
                                                    float* __restrict__ a_dst2) {
    __shared__ float w2s[D1 * OUT_DIM];   // 48 KB
    __shared__ float xs[8][D1];           // 12 KB
    int t = threadIdx.x;
#pragma unroll
    for (int i = 0; i < 12; ++i) {
        int idx = (i * 256 + t) * 4;
        *reinterpret_cast<float4*>(&w2s[idx]) = *reinterpret_cast<const float4*>(&W2[idx]);
    }
    int n0 = blockIdx.x * 8;
#pragma unroll
    for (int i = 0; i < 3; ++i) {
        int idx4 = i * 256 + t;
        int r = idx4 / 96, c4 = (idx4 % 96) * 4;
        float4 v = make_float4(0.f, 0.f, 0.f, 0.f);
        if (n0 + r < NN) {
            ushort4v u = *reinterpret_cast<const ushort4v*>(&Xb[(size_t)(n0 + r) * D1 + c4]);
            v = make_float4(bf2f(u[0]), bf2f(u[1]), bf2f(u[2]), bf2f(u[3]));
        }
        *reinterpret_cast<float4*>(&xs[r][c4]) = v;
    }
    __syncthreads();
    int c = t & 31, ln = t >> 5;
    int n = n0 + ln;
    float acc = 0.f;
#pragma unroll 8
    for (int k = 0; k < D1; ++k) acc += xs[ln][k] * w2s[k * OUT_DIM + c];
    float vs = acc * att_src2[c];
    float vd = acc * att_dst2[c];
#pragma unroll
    for (int off = 16; off; off >>= 1) {
        vs += __shfl_xor(vs, off, 32);
        vd += __shfl_xor(vd, off, 32);
    }
    if (n < NN) {
        H2b[(size_t)n * OUT_DIM + c] = f2bf(acc);
        if (c == 0) { a_src2[n] = vs; a_dst2[n] = vd; }
    }
}

// ---------------- layer-2 aggregation (+b2) -> d_out ----------------

__global__ __launch_bounds__(256) void agg2_kernel(const ushort_t* __restrict__ H2b,
                                                   const float* __restrict__ a_src,
                                                   const float* __restrict__ a_dst,
                                                   const int* __restrict__ offsets,
                                                   const int* __restrict__ srcIdx,
                                                   const float* __restrict__ b2,
                                                   float* __restrict__ out) {
    __shared__ float pl[4][CAP];
    __shared__ int   sl[4][CAP];
    int w = threadIdx.x >> 6, lane = threadIdx.x & 63;
    int n = blockIdx.x * 4 + w;
    int c = lane & 31, par = lane >> 5;
    float ad = a_dst[n];
    float m = -1e30f, den = 0.f, acc = 0.f;
    int beg = offsets[n], end = offsets[n + 1];
    for (int cbeg = beg; cbeg < end; cbeg += CAP) {
        int L = end - cbeg; if (L > CAP) L = CAP;
        float emax = -1e30f;
        for (int tI = lane; tI < L; tI += 64) {
            int s = srcIdx[cbeg + tI];
            sl[w][tI] = s;
            float e = a_src[s] + ad;
            e = e > 0.f ? e : NEG_SLOPE * e;
            pl[w][tI] = e;
            emax = fmaxf(emax, e);
        }
        float wm = emax;
#pragma unroll
        for (int o = 32; o; o >>= 1) wm = fmaxf(wm, __shfl_xor(wm, o));
        float nm = fmaxf(m, wm);
        float sc = __expf(m - nm);
        float lden = 0.f;
        for (int tI = lane; tI < L; tI += 64) {
            float p = __expf(pl[w][tI] - nm);
            pl[w][tI] = p;
            lden += p;
        }
        float wd = lden;
#pragma unroll
        for (int o = 32; o; o >>= 1) wd += __shfl_xor(wd, o);
        den = den * sc + wd;
        acc *= sc;
        m = nm;
        for (int j = par; j < L; j += 2)
            acc += pl[w][j] * bf2f(H2b[(size_t)sl[w][j] * OUT_DIM + c]);
    }
    acc += __shfl_xor(acc, 32);
    if (lane < 32) out[(size_t)n * OUT_DIM + c] = acc / den + b2[c];
}

// ---------------- launch ----------------

static inline size_t align256(size_t x) { return (x + 255) & ~size_t(255); }

extern "C" void kernel_launch(void* const* d_in, const int* in_sizes, int n_in,
                              void* d_out, int out_size, void* d_ws, size_t ws_size,
                              hipStream_t stream) {
    const float* x        = (const float*)d_in[0];
    const int*   ei       = (const int*)d_in[1];
    const float* W1       = (const float*)d_in[2];
    const float* att_src1 = (const float*)d_in[3];
    const float* att_dst1 = (const float*)d_in[4];
    const float* b1       = (const float*)d_in[5];
    const float* W2       = (const float*)d_in[6];
    const float* att_src2 = (const float*)d_in[7];
    const float* att_dst2 = (const float*)d_in[8];
    const float* b2       = (const float*)d_in[9];
    float* out = (float*)d_out;

    const int* e_src = ei;
    const int* e_dst = ei + EE;

    char* p = (char*)d_ws;
    ushort_t* H1b   = (ushort_t*)p; p += align256(sizeof(ushort_t) * (size_t)NN * D1);
    ushort_t* OUT1b = (ushort_t*)p; p += align256(sizeof(ushort_t) * (size_t)NN * D1);
    ushort_t* H2b   = (ushort_t*)p; p += align256(sizeof(ushort_t) * (size_t)NN * OUT_DIM);
    ushort_t* W1Tb  = (ushort_t*)p; p += align256(sizeof(ushort_t) * D1 * IN_DIM);
    float* AS1  = (float*)p; p += align256(sizeof(float) * NN * HEADS);
    float* AD1  = (float*)p; p += align256(sizeof(float) * NN * HEADS);
    float* AS2  = (float*)p; p += align256(sizeof(float) * NN);
    float* AD2  = (float*)p; p += align256(sizeof(float) * NN);
    int*   DEG  = (int*)p;   p += align256(sizeof(int) * NN);
    int*   OFF  = (int*)p;   p += align256(sizeof(int) * (NN + 1));
    int*   CUR  = (int*)p;   p += align256(sizeof(int) * NN);
    int*   BSUM = (int*)p;   p += align256(sizeof(int) * NBLK);
    int*   BPRE = (int*)p;   p += align256(sizeof(int) * NBLK);
    int*   SIDX = (int*)p;   p += align256(sizeof(int) * (EE + NN));

    // CSR build + weight prep
    w1t_kernel<<<dim3(D1 / 32, IN_DIM / 32), 256, 0, stream>>>(W1, W1Tb);
    deg_init_kernel<<<(NN + 255) / 256, 256, 0, stream>>>(DEG);
    hist_kernel<<<(EE + 255) / 256, 256, 0, stream>>>(e_dst, DEG);
    scan1_kernel<<<NBLK, 256, 0, stream>>>(DEG, BSUM);
    scan2_kernel<<<1, 256, 0, stream>>>(BSUM, BPRE, OFF);
    scan3_kernel<<<NBLK, 256, 0, stream>>>(DEG, BPRE, OFF, CUR);
    scatter_kernel<<<(EE + NN + 255) / 256, 256, 0, stream>>>(e_src, e_dst, CUR, SIDX);

    // layer 1
    gemm1_kernel<<<(NN + G1_BM - 1) / G1_BM, 256, 0, stream>>>(x, W1Tb, H1b);
    avec1_kernel<<<NN / 4, 256, 0, stream>>>(H1b, att_src1, att_dst1, AS1, AD1);
    agg1_kernel<<<NN / 4, 256, 0, stream>>>(H1b, AS1, AD1, OFF, SIDX, b1, OUT1b);

    // layer 2
    gemm2_kernel<<<NN / 8, 256, 0, stream>>>(OUT1b, W2, att_src2, att_dst2, H2b, AS2, AD2);
    agg2_kernel<<<NN / 4, 256, 0, stream>>>(H2b, AS2, AD2, OFF, SIDX, b2, out);
}

// Round 4
// 356.033 us; speedup vs baseline: 2.1284x; 1.1474x over previous
//
#include <hip/hip_runtime.h>
#include <hip/hip_bf16.h>

#define NN 50000
#define EE 800000
#define IN_DIM 256
#define HID 64
#define HEADS 6
#define D1 384            // HEADS*HID
#define OUT_DIM 32
#define NEG_SLOPE 0.2f
#define CAP 128           // edge chunk per node held in LDS
#define NBLK 196          // ceil(50000/256)

typedef unsigned int uint32;
typedef unsigned short ushort_t;
typedef short short8 __attribute__((ext_vector_type(8)));
typedef float f32x4 __attribute__((ext_vector_type(4)));
typedef ushort_t ushort8 __attribute__((ext_vector_type(8)));

__device__ __forceinline__ ushort_t f2bf(float f) {
    uint32 u = __builtin_bit_cast(uint32, f);
    u += 0x7fffu + ((u >> 16) & 1u);
    return (ushort_t)(u >> 16);
}
__device__ __forceinline__ float bf2f(ushort_t s) {
    uint32 u = ((uint32)s) << 16;
    return __builtin_bit_cast(float, u);
}
// dword d holds std channels (2d) in low half, (2d+1) in high half
__device__ __forceinline__ float lo16(uint32 d) { return __builtin_bit_cast(float, d << 16); }
__device__ __forceinline__ float hi16(uint32 d) { return __builtin_bit_cast(float, d & 0xffff0000u); }

// ---------------- CSR build ----------------

__global__ void deg_init_kernel(int* __restrict__ deg) {
    int i = blockIdx.x * 256 + threadIdx.x;
    if (i < NN) deg[i] = 1;   // self-loop
}

__global__ void hist_kernel(const int* __restrict__ dst, int* __restrict__ deg) {
    int i = blockIdx.x * 256 + threadIdx.x;
    if (i < EE) atomicAdd(&deg[dst[i]], 1);
}

__global__ __launch_bounds__(256) void scan1_kernel(const int* __restrict__ deg,
                                                    int* __restrict__ blockSums) {
    int t = threadIdx.x;
    int i = blockIdx.x * 256 + t;
    int v = (i < NN) ? deg[i] : 0;
#pragma unroll
    for (int o = 32; o; o >>= 1) v += __shfl_xor(v, o);
    __shared__ int ws[4];
    if ((t & 63) == 0) ws[t >> 6] = v;
    __syncthreads();
    if (t == 0) blockSums[blockIdx.x] = ws[0] + ws[1] + ws[2] + ws[3];
}

__global__ __launch_bounds__(256) void scan2_kernel(const int* __restrict__ blockSums,
                                                    int* __restrict__ blockPrefix,
                                                    int* __restrict__ offsets) {
    int t = threadIdx.x;
    int lane = t & 63, w = t >> 6;
    int v = (t < NBLK) ? blockSums[t] : 0;
    int x = v;
#pragma unroll
    for (int o = 1; o < 64; o <<= 1) {
        int y = __shfl_up(x, o);
        if (lane >= o) x += y;
    }
    __shared__ int ws[4];
    if (lane == 63) ws[w] = x;
    __syncthreads();
    int wpre = 0;
#pragma unroll
    for (int k = 0; k < 4; ++k) if (k < w) wpre += ws[k];
    int incl = x + wpre;
    if (t < NBLK) blockPrefix[t] = incl - v;
    if (t == NBLK - 1) offsets[NN] = incl;   // total == EE+NN
}

__global__ __launch_bounds__(256) void scan3_kernel(const int* __restrict__ deg,
                                                    const int* __restrict__ blockPrefix,
                                                    int* __restrict__ offsets,
                                                    int* __restrict__ cursor) {
    int t = threadIdx.x;
    int i = blockIdx.x * 256 + t;
    int lane = t & 63, w = t >> 6;
    int v = (i < NN) ? deg[i] : 0;
    int x = v;
#pragma unroll
    for (int o = 1; o < 64; o <<= 1) {
        int y = __shfl_up(x, o);
        if (lane >= o) x += y;
    }
    __shared__ int ws[4];
    if (lane == 63) ws[w] = x;
    __syncthreads();
    int wpre = 0;
#pragma unroll
    for (int k = 0; k < 4; ++k) if (k < w) wpre += ws[k];
    int excl = x + wpre - v + blockPrefix[blockIdx.x];
    if (i < NN) { offsets[i] = excl; cursor[i] = excl; }
}

__global__ void scatter_kernel(const int* __restrict__ src, const int* __restrict__ dst,
                               int* __restrict__ cursor, int* __restrict__ srcIdx) {
    int i = blockIdx.x * 256 + threadIdx.x;
    if (i >= EE + NN) return;
    int s, d;
    if (i < EE) { s = src[i]; d = dst[i]; }
    else        { s = i - EE; d = s; }
    int pos = atomicAdd(&cursor[d], 1);
    srcIdx[pos] = s;
}

// ---------------- weight prep ----------------

__global__ __launch_bounds__(256) void w1t_kernel(const float* __restrict__ W1,
                                                  ushort_t* __restrict__ W1Tb) {
    __shared__ float tile[32][33];
    int tx = threadIdx.x & 31, ty = threadIdx.x >> 5;   // 32x8
    int n0 = blockIdx.x * 32;
    int k0 = blockIdx.y * 32;
#pragma unroll
    for (int i = 0; i < 4; ++i)
        tile[ty + i * 8][tx] = W1[(k0 + ty + i * 8) * D1 + n0 + tx];
    __syncthreads();
#pragma unroll
    for (int i = 0; i < 4; ++i)
        W1Tb[(n0 + ty + i * 8) * IN_DIM + k0 + tx] = f2bf(tile[tx][ty + i * 8]);
}

// W2 [384][32] f32 -> W2Tb [32][384] bf16
__global__ __launch_bounds__(256) void w2t_kernel(const float* __restrict__ W2,
                                                  ushort_t* __restrict__ W2Tb) {
    int idx = blockIdx.x * 256 + threadIdx.x;   // 0..12287
    if (idx < D1 * OUT_DIM) {
        int k = idx >> 5, n = idx & 31;
        W2Tb[n * D1 + k] = f2bf(W2[idx]);
    }
}

// ---------------- GEMM1: H1b = bf16( x @ W1 )  via MFMA ----------------

#define G1_BM 64
#define G1_BK 64

__global__ __launch_bounds__(256) void gemm1_kernel(const float* __restrict__ A,
                                                    const ushort_t* __restrict__ Bt,
                                                    ushort_t* __restrict__ Cb) {
    __shared__ __align__(16) ushort_t As[G1_BM][G1_BK];   // 8 KB, 16B-chunk XOR swizzle
    __shared__ __align__(16) ushort_t Bs[D1][G1_BK];      // 48 KB, same swizzle
    int t = threadIdx.x;
    int m0 = blockIdx.x * G1_BM;
    int wid = t >> 6, lane = t & 63;
    int lrow = lane & 15, lk = lane >> 4;
    f32x4 acc[4][6] = {};
    for (int k0 = 0; k0 < IN_DIM; k0 += G1_BK) {
        {
            int r = t >> 3, c = t & 7;
#pragma unroll
            for (int p = 0; p < 2; ++p) {
                int row = p * 32 + r;
                int gr = m0 + row;
                float4 v0 = make_float4(0.f, 0.f, 0.f, 0.f), v1 = v0;
                if (gr < NN) {
                    const float* g = &A[(size_t)gr * IN_DIM + k0 + c * 8];
                    v0 = *reinterpret_cast<const float4*>(g);
                    v1 = *reinterpret_cast<const float4*>(g + 4);
                }
                ushort8 u;
                u[0] = f2bf(v0.x); u[1] = f2bf(v0.y); u[2] = f2bf(v0.z); u[3] = f2bf(v0.w);
                u[4] = f2bf(v1.x); u[5] = f2bf(v1.y); u[6] = f2bf(v1.z); u[7] = f2bf(v1.w);
                *reinterpret_cast<ushort8*>(&As[row][(c ^ (row & 7)) * 8]) = u;
            }
        }
        {
            int r = t >> 3, c = t & 7;
#pragma unroll
            for (int p = 0; p < 12; ++p) {
                int row = p * 32 + r;
                ushort8 u = *reinterpret_cast<const ushort8*>(&Bt[row * IN_DIM + k0 + c * 8]);
                *reinterpret_cast<ushort8*>(&Bs[row][(c ^ (row & 7)) * 8]) = u;
            }
        }
        __syncthreads();
#pragma unroll
        for (int kk = 0; kk < G1_BK; kk += 32) {
            int ckb = (kk >> 3) + lk;
            short8 af[4];
#pragma unroll
            for (int fm = 0; fm < 4; ++fm) {
                int m = fm * 16 + lrow;
                af[fm] = *reinterpret_cast<const short8*>(&As[m][(ckb ^ (m & 7)) * 8]);
            }
#pragma unroll
            for (int fn = 0; fn < 6; ++fn) {
                int n = wid * 96 + fn * 16 + lrow;
                short8 bfv = *reinterpret_cast<const short8*>(&Bs[n][(ckb ^ (n & 7)) * 8]);
#pragma unroll
                for (int fm = 0; fm < 4; ++fm)
                    acc[fm][fn] = __builtin_amdgcn_mfma_f32_16x16x32_bf16(af[fm], bfv, acc[fm][fn], 0, 0, 0);
            }
        }
        __syncthreads();
    }
#pragma unroll
    for (int fm = 0; fm < 4; ++fm) {
#pragma unroll
        for (int r = 0; r < 4; ++r) {
            int row = m0 + fm * 16 + lk * 4 + r;
            if (row < NN) {
#pragma unroll
                for (int fn = 0; fn < 6; ++fn) {
                    int col = wid * 96 + fn * 16 + lrow;
                    Cb[(size_t)row * D1 + col] = f2bf(acc[fm][fn][r]);
                }
            }
        }
    }
}

// ---------------- per-node attention coefficients, layer 1 (dword reads) ----------------

__global__ __launch_bounds__(256) void avec1_kernel(const uint32* __restrict__ H1d,
                                                    const float* __restrict__ att_src,
                                                    const float* __restrict__ att_dst,
                                                    float* __restrict__ a_src,
                                                    float* __restrict__ a_dst) {
    int n = blockIdx.x * 4 + (threadIdx.x >> 6);
    int lane = threadIdx.x & 63;
    int hb = lane >> 5;                 // head parity this lane covers
    const float2* asv = (const float2*)att_src;
    const float2* adv = (const float2*)att_dst;
    float ps[3], pd[3];
#pragma unroll
    for (int k = 0; k < 3; ++k) {
        uint32 d = H1d[(size_t)n * 192 + k * 64 + lane];
        float vlo = lo16(d), vhi = hi16(d);
        float2 a1 = asv[k * 64 + lane];
        float2 a2 = adv[k * 64 + lane];
        ps[k] = vlo * a1.x + vhi * a1.y;
        pd[k] = vlo * a2.x + vhi * a2.y;
    }
#pragma unroll
    for (int o = 16; o; o >>= 1) {
#pragma unroll
        for (int k = 0; k < 3; ++k) {
            ps[k] += __shfl_xor(ps[k], o);
            pd[k] += __shfl_xor(pd[k], o);
        }
    }
    if ((lane & 31) == 0) {
#pragma unroll
        for (int k = 0; k < 3; ++k) {
            a_src[n * HEADS + 2 * k + hb] = ps[k];
            a_dst[n * HEADS + 2 * k + hb] = pd[k];
        }
    }
}

// ---------------- layer-1 aggregation: two-phase chunked online softmax ----------------

__global__ __launch_bounds__(256) void agg1_kernel(const uint32* __restrict__ H1d,
                                                   const float* __restrict__ a_src,
                                                   const float* __restrict__ a_dst,
                                                   const int* __restrict__ offsets,
                                                   const int* __restrict__ srcIdx,
                                                   const float* __restrict__ b1,
                                                   uint32* __restrict__ out1d) {
    __shared__ float pl[4][CAP][HEADS];   // 12 KB
    __shared__ int   sl[4][CAP];          // 2 KB
    int w = threadIdx.x >> 6, lane = threadIdx.x & 63;
    int hb = lane >> 5;
    int n = blockIdx.x * 4 + w;
    const float2* asv = (const float2*)a_src;
    float ad[HEADS], m[HEADS], den[HEADS];
    float acc[6];   // acc[2k],acc[2k+1] = channels (2*lane+128k)&... of head 2k+hb
#pragma unroll
    for (int h = 0; h < HEADS; ++h) {
        ad[h] = a_dst[n * HEADS + h];
        m[h] = -1e30f; den[h] = 0.f;
    }
#pragma unroll
    for (int k = 0; k < 6; ++k) acc[k] = 0.f;
    int beg = offsets[n], end = offsets[n + 1];
    for (int cbeg = beg; cbeg < end; cbeg += CAP) {
        int L = end - cbeg; if (L > CAP) L = CAP;
        // ---- phase A: lanes over edges ----
        float emax[HEADS];
#pragma unroll
        for (int h = 0; h < HEADS; ++h) emax[h] = -1e30f;
        for (int tI = lane; tI < L; tI += 64) {
            int s = srcIdx[cbeg + tI];
            sl[w][tI] = s;
            float2 e0 = asv[s * 3 + 0];
            float2 e1 = asv[s * 3 + 1];
            float2 e2 = asv[s * 3 + 2];
            float ev[6] = {e0.x, e0.y, e1.x, e1.y, e2.x, e2.y};
#pragma unroll
            for (int h = 0; h < HEADS; ++h) {
                float e = ev[h] + ad[h];
                e = e > 0.f ? e : NEG_SLOPE * e;
                pl[w][tI][h] = e;
                emax[h] = fmaxf(emax[h], e);
            }
        }
        float nm[HEADS], sc[HEADS];
#pragma unroll
        for (int h = 0; h < HEADS; ++h) {
            float wm = emax[h];
#pragma unroll
            for (int o = 32; o; o >>= 1) wm = fmaxf(wm, __shfl_xor(wm, o));
            nm[h] = fmaxf(m[h], wm);
            sc[h] = __expf(m[h] - nm[h]);
        }
        float lden[HEADS] = {0.f, 0.f, 0.f, 0.f, 0.f, 0.f};
        for (int tI = lane; tI < L; tI += 64) {
#pragma unroll
            for (int h = 0; h < HEADS; ++h) {
                float p = __expf(pl[w][tI][h] - nm[h]);
                pl[w][tI][h] = p;
                lden[h] += p;
            }
        }
#pragma unroll
        for (int h = 0; h < HEADS; ++h) {
            float wd = lden[h];
#pragma unroll
            for (int o = 32; o; o >>= 1) wd += __shfl_xor(wd, o);
            den[h] = den[h] * sc[h] + wd;
            m[h] = nm[h];
        }
        // rescale acc: acc pair k belongs to head 2k+hb
        float scSel[3];
#pragma unroll
        for (int k = 0; k < 3; ++k) scSel[k] = hb ? sc[2 * k + 1] : sc[2 * k];
#pragma unroll
        for (int k = 0; k < 3; ++k) { acc[2 * k] *= scSel[k]; acc[2 * k + 1] *= scSel[k]; }
        // ---- phase B: lanes over dwords of the row, 3 coalesced dword gathers/edge ----
#pragma unroll 2
        for (int j = 0; j < L; ++j) {
            int s = sl[w][j];
            const uint32* hr = H1d + (size_t)s * 192 + lane;
            const float* pj = &pl[w][j][hb];
            float p0 = pj[0], p1 = pj[2], p2 = pj[4];
            uint32 d0 = hr[0], d1 = hr[64], d2 = hr[128];
            acc[0] += p0 * lo16(d0); acc[1] += p0 * hi16(d0);
            acc[2] += p1 * lo16(d1); acc[3] += p1 * hi16(d1);
            acc[4] += p2 * lo16(d2); acc[5] += p2 * hi16(d2);
        }
    }
    float dsel[3];
#pragma unroll
    for (int k = 0; k < 3; ++k) dsel[k] = hb ? den[2 * k + 1] : den[2 * k];
    const float2* b1v = (const float2*)b1;
#pragma unroll
    for (int k = 0; k < 3; ++k) {
        float2 bb = b1v[k * 64 + lane];
        float v0 = fmaxf(acc[2 * k]     / dsel[k] + bb.x, 0.f);
        float v1 = fmaxf(acc[2 * k + 1] / dsel[k] + bb.y, 0.f);
        out1d[(size_t)n * 192 + k * 64 + lane] = (uint32)f2bf(v0) | ((uint32)f2bf(v1) << 16);
    }
}

// ---------------- GEMM2 via MFMA (+ fused a_src2/a_dst2) ----------------
// block: 256 rows x 32 cols, 4 waves (wave w: rows w*64..), K=384 in 6 chunks of 64

#define G2_ROWS 256

__global__ __launch_bounds__(256) void gemm2_kernel(const ushort_t* __restrict__ Xb,
                                                    const ushort_t* __restrict__ W2Tb,
                                                    const float* __restrict__ att_src2,
                                                    const float* __restrict__ att_dst2,
                                                    ushort_t* __restrict__ H2b,
                                                    float* __restrict__ a_src2,
                                                    float* __restrict__ a_dst2) {
    __shared__ __align__(16) ushort_t Ws[OUT_DIM][D1];     // 24 KB, swizzled per 64-span
    __shared__ __align__(16) ushort_t Xs[G2_ROWS][64];     // 32 KB, swizzled
    int t = threadIdx.x;
    int wid = t >> 6, lane = t & 63;
    int lrow = lane & 15, lk = lane >> 4;
    int m0 = blockIdx.x * G2_ROWS;
    // stage W2T whole: 32 rows x 48 chunks = 1536 chunks, 6 per thread
#pragma unroll
    for (int p = 0; p < 6; ++p) {
        int chunk = p * 256 + t;
        int nr = chunk / 48, c = chunk % 48;
        ushort8 u = *reinterpret_cast<const ushort8*>(&W2Tb[nr * D1 + c * 8]);
        int span = c >> 3, cc = c & 7;
        *reinterpret_cast<ushort8*>(&Ws[nr][(cc ^ (nr & 7)) * 8 + span * 64]) = u;
    }
    f32x4 acc[4][2] = {};
    for (int kc = 0; kc < 6; ++kc) {
        int k0 = kc * 64;
        {
            int r = t >> 3, c = t & 7;
#pragma unroll
            for (int p = 0; p < 8; ++p) {
                int row = p * 32 + r;
                int gr = m0 + row;
                ushort8 u = {0, 0, 0, 0, 0, 0, 0, 0};
                if (gr < NN) u = *reinterpret_cast<const ushort8*>(&Xb[(size_t)gr * D1 + k0 + c * 8]);
                *reinterpret_cast<ushort8*>(&Xs[row][(c ^ (row & 7)) * 8]) = u;
            }
        }
        __syncthreads();
#pragma unroll
        for (int kk = 0; kk < 64; kk += 32) {
            int ckb = (kk >> 3) + lk;
            short8 af[4];
#pragma unroll
            for (int fm = 0; fm < 4; ++fm) {
                int mm = wid * 64 + fm * 16 + lrow;
                af[fm] = *reinterpret_cast<const short8*>(&Xs[mm][(ckb ^ (mm & 7)) * 8]);
            }
#pragma unroll
            for (int fn = 0; fn < 2; ++fn) {
                int nn2 = fn * 16 + lrow;
                short8 bfv = *reinterpret_cast<const short8*>(&Ws[nn2][(ckb ^ (nn2 & 7)) * 8 + kc * 64]);
#pragma unroll
                for (int fm = 0; fm < 4; ++fm)
                    acc[fm][fn] = __builtin_amdgcn_mfma_f32_16x16x32_bf16(af[fm], bfv, acc[fm][fn], 0, 0, 0);
            }
        }
        __syncthreads();
    }
    float as2a = att_src2[lrow], as2b = att_src2[16 + lrow];
    float ad2a = att_dst2[lrow], ad2b = att_dst2[16 + lrow];
#pragma unroll
    for (int fm = 0; fm < 4; ++fm) {
#pragma unroll
        for (int r = 0; r < 4; ++r) {
            int row = m0 + wid * 64 + fm * 16 + lk * 4 + r;   // uniform across 16-lane group
            float h0 = acc[fm][0][r], h1 = acc[fm][1][r];
            float vs = h0 * as2a + h1 * as2b;
            float vd = h0 * ad2a + h1 * ad2b;
#pragma unroll
            for (int o = 8; o; o >>= 1) {
                vs += __shfl_xor(vs, o);
                vd += __shfl_xor(vd, o);
            }
            if (row < NN) {
                H2b[(size_t)row * OUT_DIM + lrow]      = f2bf(h0);
                H2b[(size_t)row * OUT_DIM + 16 + lrow] = f2bf(h1);
                if (lrow == 0) { a_src2[row] = vs; a_dst2[row] = vd; }
            }
        }
    }
}

// ---------------- layer-2 aggregation (+b2) -> d_out ----------------

__global__ __launch_bounds__(256) void agg2_kernel(const ushort_t* __restrict__ H2b,
                                                   const float* __restrict__ a_src,
                                                   const float* __restrict__ a_dst,
                                                   const int* __restrict__ offsets,
                                                   const int* __restrict__ srcIdx,
                                                   const float* __restrict__ b2,
                                                   float* __restrict__ out) {
    __shared__ float pl[4][CAP];
    __shared__ int   sl[4][CAP];
    int w = threadIdx.x >> 6, lane = threadIdx.x & 63;
    int n = blockIdx.x * 4 + w;
    int q = lane & 15, par = lane >> 4;   // 4 edges in parallel, lane covers chans 2q,2q+1
    const uint32* H2d = (const uint32*)H2b;
    float ad = a_dst[n];
    float m = -1e30f, den = 0.f, ax = 0.f, ay = 0.f;
    int beg = offsets[n], end = offsets[n + 1];
    for (int cbeg = beg; cbeg < end; cbeg += CAP) {
        int L = end - cbeg; if (L > CAP) L = CAP;
        float emax = -1e30f;
        for (int tI = lane; tI < L; tI += 64) {
            int s = srcIdx[cbeg + tI];
            sl[w][tI] = s;
            float e = a_src[s] + ad;
            e = e > 0.f ? e : NEG_SLOPE * e;
            pl[w][tI] = e;
            emax = fmaxf(emax, e);
        }
        float wm = emax;
#pragma unroll
        for (int o = 32; o; o >>= 1) wm = fmaxf(wm, __shfl_xor(wm, o));
        float nm = fmaxf(m, wm);
        float sc = __expf(m - nm);
        float lden = 0.f;
        for (int tI = lane; tI < L; tI += 64) {
            float p = __expf(pl[w][tI] - nm);
            pl[w][tI] = p;
            lden += p;
        }
        float wd = lden;
#pragma unroll
        for (int o = 32; o; o >>= 1) wd += __shfl_xor(wd, o);
        den = den * sc + wd;
        ax *= sc; ay *= sc;
        m = nm;
        for (int j = 0; j < L; j += 4) {
            int jj = j + par;
            if (jj < L) {
                int s = sl[w][jj];
                float p = pl[w][jj];
                uint32 d = H2d[(size_t)s * 16 + q];
                ax += p * lo16(d);
                ay += p * hi16(d);
            }
        }
    }
    ax += __shfl_xor(ax, 16); ax += __shfl_xor(ax, 32);
    ay += __shfl_xor(ay, 16); ay += __shfl_xor(ay, 32);
    if (lane < 16) {
        float2 bb = ((const float2*)b2)[q];
        float2 o;
        o.x = ax / den + bb.x;
        o.y = ay / den + bb.y;
        ((float2*)out)[(size_t)n * 16 + q] = o;
    }
}

// ---------------- launch ----------------

static inline size_t align256(size_t x) { return (x + 255) & ~size_t(255); }

extern "C" void kernel_launch(void* const* d_in, const int* in_sizes, int n_in,
                              void* d_out, int out_size, void* d_ws, size_t ws_size,
                              hipStream_t stream) {
    const float* x        = (const float*)d_in[0];
    const int*   ei       = (const int*)d_in[1];
    const float* W1       = (const float*)d_in[2];
    const float* att_src1 = (const float*)d_in[3];
    const float* att_dst1 = (const float*)d_in[4];
    const float* b1       = (const float*)d_in[5];
    const float* W2       = (const float*)d_in[6];
    const float* att_src2 = (const float*)d_in[7];
    const float* att_dst2 = (const float*)d_in[8];
    const float* b2       = (const float*)d_in[9];
    float* out = (float*)d_out;

    const int* e_src = ei;
    const int* e_dst = ei + EE;

    char* p = (char*)d_ws;
    ushort_t* H1b   = (ushort_t*)p; p += align256(sizeof(ushort_t) * (size_t)NN * D1);
    ushort_t* OUT1b = (ushort_t*)p; p += align256(sizeof(ushort_t) * (size_t)NN * D1);
    ushort_t* H2b   = (ushort_t*)p; p += align256(sizeof(ushort_t) * (size_t)NN * OUT_DIM);
    ushort_t* W1Tb  = (ushort_t*)p; p += align256(sizeof(ushort_t) * D1 * IN_DIM);
    ushort_t* W2Tb  = (ushort_t*)p; p += align256(sizeof(ushort_t) * D1 * OUT_DIM);
    float* AS1  = (float*)p; p += align256(sizeof(float) * NN * HEADS);
    float* AD1  = (float*)p; p += align256(sizeof(float) * NN * HEADS);
    float* AS2  = (float*)p; p += align256(sizeof(float) * NN);
    float* AD2  = (float*)p; p += align256(sizeof(float) * NN);
    int*   DEG  = (int*)p;   p += align256(sizeof(int) * NN);
    int*   OFF  = (int*)p;   p += align256(sizeof(int) * (NN + 1));
    int*   CUR  = (int*)p;   p += align256(sizeof(int) * NN);
    int*   BSUM = (int*)p;   p += align256(sizeof(int) * NBLK);
    int*   BPRE = (int*)p;   p += align256(sizeof(int) * NBLK);
    int*   SIDX = (int*)p;   p += align256(sizeof(int) * (EE + NN));

    // CSR build + weight prep
    w1t_kernel<<<dim3(D1 / 32, IN_DIM / 32), 256, 0, stream>>>(W1, W1Tb);
    w2t_kernel<<<48, 256, 0, stream>>>(W2, W2Tb);
    deg_init_kernel<<<(NN + 255) / 256, 256, 0, stream>>>(DEG);
    hist_kernel<<<(EE + 255) / 256, 256, 0, stream>>>(e_dst, DEG);
    scan1_kernel<<<NBLK, 256, 0, stream>>>(DEG, BSUM);
    scan2_kernel<<<1, 256, 0, stream>>>(BSUM, BPRE, OFF);
    scan3_kernel<<<NBLK, 256, 0, stream>>>(DEG, BPRE, OFF, CUR);
    scatter_kernel<<<(EE + NN + 255) / 256, 256, 0, stream>>>(e_src, e_dst, CUR, SIDX);

    // layer 1
    gemm1_kernel<<<(NN + G1_BM - 1) / G1_BM, 256, 0, stream>>>(x, W1Tb, H1b);
    avec1_kernel<<<NN / 4, 256, 0, stream>>>((const uint32*)H1b, att_src1, att_dst1, AS1, AD1);
    agg1_kernel<<<NN / 4, 256, 0, stream>>>((const uint32*)H1b, AS1, AD1, OFF, SIDX, b1, (uint32*)OUT1b);

    // layer 2
    gemm2_kernel<<<(NN + G2_ROWS - 1) / G2_ROWS, 256, 0, stream>>>(OUT1b, W2Tb, att_src2, att_dst2, H2b, AS2, AD2);
    agg2_kernel<<<NN / 4, 256, 0, stream>>>(H2b, AS2, AD2, OFF, SIDX, b2, out);
}

// Round 5
// 339.416 us; speedup vs baseline: 2.2326x; 1.0490x over previous
//
#include <hip/hip_runtime.h>
#include <hip/hip_bf16.h>

#define NN 50000
#define EE 800000
#define IN_DIM 256
#define HID 64
#define HEADS 6
#define D1 384            // HEADS*HID
#define OUT_DIM 32
#define NEG_SLOPE 0.2f
#define CAP 128           // edge chunk per node held in LDS
#define NBLK 196          // ceil(50000/256)

typedef unsigned int uint32;
typedef unsigned short ushort_t;
typedef short short8 __attribute__((ext_vector_type(8)));
typedef float f32x4 __attribute__((ext_vector_type(4)));
typedef ushort_t ushort8 __attribute__((ext_vector_type(8)));

__device__ __forceinline__ ushort_t f2bf(float f) {
    uint32 u = __builtin_bit_cast(uint32, f);
    u += 0x7fffu + ((u >> 16) & 1u);
    return (ushort_t)(u >> 16);
}
__device__ __forceinline__ float bf2f(ushort_t s) {
    uint32 u = ((uint32)s) << 16;
    return __builtin_bit_cast(float, u);
}
// dword d holds std channels (2d) in low half, (2d+1) in high half
__device__ __forceinline__ float lo16(uint32 d) { return __builtin_bit_cast(float, d << 16); }
__device__ __forceinline__ float hi16(uint32 d) { return __builtin_bit_cast(float, d & 0xffff0000u); }

// ---------------- CSR build ----------------

__global__ void deg_init_kernel(int* __restrict__ deg) {
    int i = blockIdx.x * 256 + threadIdx.x;
    if (i < NN) deg[i] = 1;   // self-loop
}

__global__ void hist_kernel(const int* __restrict__ dst, int* __restrict__ deg) {
    int i = blockIdx.x * 256 + threadIdx.x;
    if (i < EE) atomicAdd(&deg[dst[i]], 1);
}

__global__ __launch_bounds__(256) void scan1_kernel(const int* __restrict__ deg,
                                                    int* __restrict__ blockSums) {
    int t = threadIdx.x;
    int i = blockIdx.x * 256 + t;
    int v = (i < NN) ? deg[i] : 0;
#pragma unroll
    for (int o = 32; o; o >>= 1) v += __shfl_xor(v, o);
    __shared__ int ws[4];
    if ((t & 63) == 0) ws[t >> 6] = v;
    __syncthreads();
    if (t == 0) blockSums[blockIdx.x] = ws[0] + ws[1] + ws[2] + ws[3];
}

__global__ __launch_bounds__(256) void scan2_kernel(const int* __restrict__ blockSums,
                                                    int* __restrict__ blockPrefix,
                                                    int* __restrict__ offsets) {
    int t = threadIdx.x;
    int lane = t & 63, w = t >> 6;
    int v = (t < NBLK) ? blockSums[t] : 0;
    int x = v;
#pragma unroll
    for (int o = 1; o < 64; o <<= 1) {
        int y = __shfl_up(x, o);
        if (lane >= o) x += y;
    }
    __shared__ int ws[4];
    if (lane == 63) ws[w] = x;
    __syncthreads();
    int wpre = 0;
#pragma unroll
    for (int k = 0; k < 4; ++k) if (k < w) wpre += ws[k];
    int incl = x + wpre;
    if (t < NBLK) blockPrefix[t] = incl - v;
    if (t == NBLK - 1) offsets[NN] = incl;   // total == EE+NN
}

__global__ __launch_bounds__(256) void scan3_kernel(const int* __restrict__ deg,
                                                    const int* __restrict__ blockPrefix,
                                                    int* __restrict__ offsets,
                                                    int* __restrict__ cursor) {
    int t = threadIdx.x;
    int i = blockIdx.x * 256 + t;
    int lane = t & 63, w = t >> 6;
    int v = (i < NN) ? deg[i] : 0;
    int x = v;
#pragma unroll
    for (int o = 1; o < 64; o <<= 1) {
        int y = __shfl_up(x, o);
        if (lane >= o) x += y;
    }
    __shared__ int ws[4];
    if (lane == 63) ws[w] = x;
    __syncthreads();
    int wpre = 0;
#pragma unroll
    for (int k = 0; k < 4; ++k) if (k < w) wpre += ws[k];
    int excl = x + wpre - v + blockPrefix[blockIdx.x];
    if (i < NN) { offsets[i] = excl; cursor[i] = excl; }
}

__global__ void scatter_kernel(const int* __restrict__ src, const int* __restrict__ dst,
                               int* __restrict__ cursor, int* __restrict__ srcIdx) {
    int i = blockIdx.x * 256 + threadIdx.x;
    if (i >= EE + NN) return;
    int s, d;
    if (i < EE) { s = src[i]; d = dst[i]; }
    else        { s = i - EE; d = s; }
    int pos = atomicAdd(&cursor[d], 1);
    srcIdx[pos] = s;
}

// ---------------- weight prep ----------------

__global__ __launch_bounds__(256) void w1t_kernel(const float* __restrict__ W1,
                                                  ushort_t* __restrict__ W1Tb) {
    __shared__ float tile[32][33];
    int tx = threadIdx.x & 31, ty = threadIdx.x >> 5;   // 32x8
    int n0 = blockIdx.x * 32;
    int k0 = blockIdx.y * 32;
#pragma unroll
    for (int i = 0; i < 4; ++i)
        tile[ty + i * 8][tx] = W1[(k0 + ty + i * 8) * D1 + n0 + tx];
    __syncthreads();
#pragma unroll
    for (int i = 0; i < 4; ++i)
        W1Tb[(n0 + ty + i * 8) * IN_DIM + k0 + tx] = f2bf(tile[tx][ty + i * 8]);
}

// W2 [384][32] f32 -> W2Tb [32][384] bf16
__global__ __launch_bounds__(256) void w2t_kernel(const float* __restrict__ W2,
                                                  ushort_t* __restrict__ W2Tb) {
    int idx = blockIdx.x * 256 + threadIdx.x;   // 0..12287
    if (idx < D1 * OUT_DIM) {
        int k = idx >> 5, n = idx & 31;
        W2Tb[n * D1 + k] = f2bf(W2[idx]);
    }
}

// ---------------- GEMM1: H1b = bf16( x @ W1 )  via MFMA ----------------

#define G1_BM 64
#define G1_BK 64

__global__ __launch_bounds__(256) void gemm1_kernel(const float* __restrict__ A,
                                                    const ushort_t* __restrict__ Bt,
                                                    ushort_t* __restrict__ Cb) {
    __shared__ __align__(16) ushort_t As[G1_BM][G1_BK];   // 8 KB, 16B-chunk XOR swizzle
    __shared__ __align__(16) ushort_t Bs[D1][G1_BK];      // 48 KB, same swizzle
    int t = threadIdx.x;
    int m0 = blockIdx.x * G1_BM;
    int wid = t >> 6, lane = t & 63;
    int lrow = lane & 15, lk = lane >> 4;
    f32x4 acc[4][6] = {};
    for (int k0 = 0; k0 < IN_DIM; k0 += G1_BK) {
        {
            int r = t >> 3, c = t & 7;
#pragma unroll
            for (int p = 0; p < 2; ++p) {
                int row = p * 32 + r;
                int gr = m0 + row;
                float4 v0 = make_float4(0.f, 0.f, 0.f, 0.f), v1 = v0;
                if (gr < NN) {
                    const float* g = &A[(size_t)gr * IN_DIM + k0 + c * 8];
                    v0 = *reinterpret_cast<const float4*>(g);
                    v1 = *reinterpret_cast<const float4*>(g + 4);
                }
                ushort8 u;
                u[0] = f2bf(v0.x); u[1] = f2bf(v0.y); u[2] = f2bf(v0.z); u[3] = f2bf(v0.w);
                u[4] = f2bf(v1.x); u[5] = f2bf(v1.y); u[6] = f2bf(v1.z); u[7] = f2bf(v1.w);
                *reinterpret_cast<ushort8*>(&As[row][(c ^ (row & 7)) * 8]) = u;
            }
        }
        {
            int r = t >> 3, c = t & 7;
#pragma unroll
            for (int p = 0; p < 12; ++p) {
                int row = p * 32 + r;
                ushort8 u = *reinterpret_cast<const ushort8*>(&Bt[row * IN_DIM + k0 + c * 8]);
                *reinterpret_cast<ushort8*>(&Bs[row][(c ^ (row & 7)) * 8]) = u;
            }
        }
        __syncthreads();
#pragma unroll
        for (int kk = 0; kk < G1_BK; kk += 32) {
            int ckb = (kk >> 3) + lk;
            short8 af[4];
#pragma unroll
            for (int fm = 0; fm < 4; ++fm) {
                int m = fm * 16 + lrow;
                af[fm] = *reinterpret_cast<const short8*>(&As[m][(ckb ^ (m & 7)) * 8]);
            }
#pragma unroll
            for (int fn = 0; fn < 6; ++fn) {
                int n = wid * 96 + fn * 16 + lrow;
                short8 bfv = *reinterpret_cast<const short8*>(&Bs[n][(ckb ^ (n & 7)) * 8]);
#pragma unroll
                for (int fm = 0; fm < 4; ++fm)
                    acc[fm][fn] = __builtin_amdgcn_mfma_f32_16x16x32_bf16(af[fm], bfv, acc[fm][fn], 0, 0, 0);
            }
        }
        __syncthreads();
    }
#pragma unroll
    for (int fm = 0; fm < 4; ++fm) {
#pragma unroll
        for (int r = 0; r < 4; ++r) {
            int row = m0 + fm * 16 + lk * 4 + r;
            if (row < NN) {
#pragma unroll
                for (int fn = 0; fn < 6; ++fn) {
                    int col = wid * 96 + fn * 16 + lrow;
                    Cb[(size_t)row * D1 + col] = f2bf(acc[fm][fn][r]);
                }
            }
        }
    }
}

// ---------------- per-node attention coefficients, layer 1 (dword reads) ----------------

__global__ __launch_bounds__(256) void avec1_kernel(const uint32* __restrict__ H1d,
                                                    const float* __restrict__ att_src,
                                                    const float* __restrict__ att_dst,
                                                    float* __restrict__ a_src,
                                                    float* __restrict__ a_dst) {
    int n = blockIdx.x * 4 + (threadIdx.x >> 6);
    int lane = threadIdx.x & 63;
    int hb = lane >> 5;                 // head parity this lane covers
    const float2* asv = (const float2*)att_src;
    const float2* adv = (const float2*)att_dst;
    float ps[3], pd[3];
#pragma unroll
    for (int k = 0; k < 3; ++k) {
        uint32 d = H1d[(size_t)n * 192 + k * 64 + lane];
        float vlo = lo16(d), vhi = hi16(d);
        float2 a1 = asv[k * 64 + lane];
        float2 a2 = adv[k * 64 + lane];
        ps[k] = vlo * a1.x + vhi * a1.y;
        pd[k] = vlo * a2.x + vhi * a2.y;
    }
#pragma unroll
    for (int o = 16; o; o >>= 1) {
#pragma unroll
        for (int k = 0; k < 3; ++k) {
            ps[k] += __shfl_xor(ps[k], o);
            pd[k] += __shfl_xor(pd[k], o);
        }
    }
    if ((lane & 31) == 0) {
#pragma unroll
        for (int k = 0; k < 3; ++k) {
            a_src[n * HEADS + 2 * k + hb] = ps[k];
            a_dst[n * HEADS + 2 * k + hb] = pd[k];
        }
    }
}

// ---------------- layer-1 aggregation: exp-direct two-phase ----------------
// pl head-major (+1 pad): phase-A writes stride-1, phase-B reads 2-addr broadcast.
// No max-subtraction (e bounded): removes rescale state; den reduced once at end.

__global__ __launch_bounds__(256, 4) void agg1_kernel(const uint32* __restrict__ H1d,
                                                      const float* __restrict__ a_src,
                                                      const float* __restrict__ a_dst,
                                                      const int* __restrict__ offsets,
                                                      const int* __restrict__ srcIdx,
                                                      const float* __restrict__ b1,
                                                      uint32* __restrict__ out1d) {
    __shared__ float pl[4][HEADS][CAP + 1];   // ~12.4 KB
    __shared__ int   sl[4][CAP];              // 2 KB
    int w = threadIdx.x >> 6, lane = threadIdx.x & 63;
    int hb = lane >> 5;
    int n = blockIdx.x * 4 + w;
    const float2* asv = (const float2*)a_src;
    float ad[HEADS];
#pragma unroll
    for (int h = 0; h < HEADS; ++h) ad[h] = a_dst[n * HEADS + h];
    float ldn[HEADS] = {0.f, 0.f, 0.f, 0.f, 0.f, 0.f};
    float acc[6] = {0.f, 0.f, 0.f, 0.f, 0.f, 0.f};
    int beg = offsets[n], end = offsets[n + 1];
    for (int cbeg = beg; cbeg < end; cbeg += CAP) {
        int L = end - cbeg; if (L > CAP) L = CAP;
        // ---- phase A: lanes over edges ----
        for (int tI = lane; tI < L; tI += 64) {
            int s = srcIdx[cbeg + tI];
            sl[w][tI] = s;
            float2 e0 = asv[s * 3 + 0];
            float2 e1 = asv[s * 3 + 1];
            float2 e2 = asv[s * 3 + 2];
            float ev[6] = {e0.x, e0.y, e1.x, e1.y, e2.x, e2.y};
#pragma unroll
            for (int h = 0; h < HEADS; ++h) {
                float e = ev[h] + ad[h];
                e = e > 0.f ? e : NEG_SLOPE * e;
                float p = __expf(e);
                pl[w][h][tI] = p;
                ldn[h] += p;
            }
        }
        // ---- phase B: lanes over dwords, 2 edges in flight ----
        int j = 0;
        for (; j + 2 <= L; j += 2) {
            int s0 = sl[w][j], s1 = sl[w][j + 1];
            const uint32* h0 = H1d + (size_t)s0 * 192 + lane;
            const uint32* h1 = H1d + (size_t)s1 * 192 + lane;
            uint32 x0 = h0[0], x1 = h0[64], x2 = h0[128];
            uint32 y0 = h1[0], y1 = h1[64], y2 = h1[128];
            float p0 = pl[w][hb][j],     p1 = pl[w][2 + hb][j],     p2 = pl[w][4 + hb][j];
            float q0 = pl[w][hb][j + 1], q1 = pl[w][2 + hb][j + 1], q2 = pl[w][4 + hb][j + 1];
            acc[0] += p0 * lo16(x0); acc[1] += p0 * hi16(x0);
            acc[2] += p1 * lo16(x1); acc[3] += p1 * hi16(x1);
            acc[4] += p2 * lo16(x2); acc[5] += p2 * hi16(x2);
            acc[0] += q0 * lo16(y0); acc[1] += q0 * hi16(y0);
            acc[2] += q1 * lo16(y1); acc[3] += q1 * hi16(y1);
            acc[4] += q2 * lo16(y2); acc[5] += q2 * hi16(y2);
        }
        if (j < L) {
            int s0 = sl[w][j];
            const uint32* h0 = H1d + (size_t)s0 * 192 + lane;
            uint32 x0 = h0[0], x1 = h0[64], x2 = h0[128];
            float p0 = pl[w][hb][j], p1 = pl[w][2 + hb][j], p2 = pl[w][4 + hb][j];
            acc[0] += p0 * lo16(x0); acc[1] += p0 * hi16(x0);
            acc[2] += p1 * lo16(x1); acc[3] += p1 * hi16(x1);
            acc[4] += p2 * lo16(x2); acc[5] += p2 * hi16(x2);
        }
    }
#pragma unroll
    for (int h = 0; h < HEADS; ++h) {
#pragma unroll
        for (int o = 32; o; o >>= 1) ldn[h] += __shfl_xor(ldn[h], o);
    }
    float dsel[3];
#pragma unroll
    for (int k = 0; k < 3; ++k) dsel[k] = hb ? ldn[2 * k + 1] : ldn[2 * k];
    const float2* b1v = (const float2*)b1;
#pragma unroll
    for (int k = 0; k < 3; ++k) {
        float2 bb = b1v[k * 64 + lane];
        float v0 = fmaxf(acc[2 * k]     / dsel[k] + bb.x, 0.f);
        float v1 = fmaxf(acc[2 * k + 1] / dsel[k] + bb.y, 0.f);
        out1d[(size_t)n * 192 + k * 64 + lane] = (uint32)f2bf(v0) | ((uint32)f2bf(v1) << 16);
    }
}

// ---------------- GEMM2 via MFMA (+ fused a_src2/a_dst2) ----------------

#define G2_ROWS 256

__global__ __launch_bounds__(256) void gemm2_kernel(const ushort_t* __restrict__ Xb,
                                                    const ushort_t* __restrict__ W2Tb,
                                                    const float* __restrict__ att_src2,
                                                    const float* __restrict__ att_dst2,
                                                    ushort_t* __restrict__ H2b,
                                                    float* __restrict__ a_src2,
                                                    float* __restrict__ a_dst2) {
    __shared__ __align__(16) ushort_t Ws[OUT_DIM][D1];     // 24 KB, swizzled per 64-span
    __shared__ __align__(16) ushort_t Xs[G2_ROWS][64];     // 32 KB, swizzled
    int t = threadIdx.x;
    int wid = t >> 6, lane = t & 63;
    int lrow = lane & 15, lk = lane >> 4;
    int m0 = blockIdx.x * G2_ROWS;
#pragma unroll
    for (int p = 0; p < 6; ++p) {
        int chunk = p * 256 + t;
        int nr = chunk / 48, c = chunk % 48;
        ushort8 u = *reinterpret_cast<const ushort8*>(&W2Tb[nr * D1 + c * 8]);
        int span = c >> 3, cc = c & 7;
        *reinterpret_cast<ushort8*>(&Ws[nr][(cc ^ (nr & 7)) * 8 + span * 64]) = u;
    }
    f32x4 acc[4][2] = {};
    for (int kc = 0; kc < 6; ++kc) {
        int k0 = kc * 64;
        {
            int r = t >> 3, c = t & 7;
#pragma unroll
            for (int p = 0; p < 8; ++p) {
                int row = p * 32 + r;
                int gr = m0 + row;
                ushort8 u = {0, 0, 0, 0, 0, 0, 0, 0};
                if (gr < NN) u = *reinterpret_cast<const ushort8*>(&Xb[(size_t)gr * D1 + k0 + c * 8]);
                *reinterpret_cast<ushort8*>(&Xs[row][(c ^ (row & 7)) * 8]) = u;
            }
        }
        __syncthreads();
#pragma unroll
        for (int kk = 0; kk < 64; kk += 32) {
            int ckb = (kk >> 3) + lk;
            short8 af[4];
#pragma unroll
            for (int fm = 0; fm < 4; ++fm) {
                int mm = wid * 64 + fm * 16 + lrow;
                af[fm] = *reinterpret_cast<const short8*>(&Xs[mm][(ckb ^ (mm & 7)) * 8]);
            }
#pragma unroll
            for (int fn = 0; fn < 2; ++fn) {
                int nn2 = fn * 16 + lrow;
                short8 bfv = *reinterpret_cast<const short8*>(&Ws[nn2][(ckb ^ (nn2 & 7)) * 8 + kc * 64]);
#pragma unroll
                for (int fm = 0; fm < 4; ++fm)
                    acc[fm][fn] = __builtin_amdgcn_mfma_f32_16x16x32_bf16(af[fm], bfv, acc[fm][fn], 0, 0, 0);
            }
        }
        __syncthreads();
    }
    float as2a = att_src2[lrow], as2b = att_src2[16 + lrow];
    float ad2a = att_dst2[lrow], ad2b = att_dst2[16 + lrow];
#pragma unroll
    for (int fm = 0; fm < 4; ++fm) {
#pragma unroll
        for (int r = 0; r < 4; ++r) {
            int row = m0 + wid * 64 + fm * 16 + lk * 4 + r;
            float h0 = acc[fm][0][r], h1 = acc[fm][1][r];
            float vs = h0 * as2a + h1 * as2b;
            float vd = h0 * ad2a + h1 * ad2b;
#pragma unroll
            for (int o = 8; o; o >>= 1) {
                vs += __shfl_xor(vs, o);
                vd += __shfl_xor(vd, o);
            }
            if (row < NN) {
                H2b[(size_t)row * OUT_DIM + lrow]      = f2bf(h0);
                H2b[(size_t)row * OUT_DIM + 16 + lrow] = f2bf(h1);
                if (lrow == 0) { a_src2[row] = vs; a_dst2[row] = vd; }
            }
        }
    }
}

// ---------------- layer-2 aggregation: exp-direct (+b2) -> d_out ----------------

__global__ __launch_bounds__(256, 4) void agg2_kernel(const ushort_t* __restrict__ H2b,
                                                      const float* __restrict__ a_src,
                                                      const float* __restrict__ a_dst,
                                                      const int* __restrict__ offsets,
                                                      const int* __restrict__ srcIdx,
                                                      const float* __restrict__ b2,
                                                      float* __restrict__ out) {
    __shared__ float pl[4][CAP];
    __shared__ int   sl[4][CAP];
    int w = threadIdx.x >> 6, lane = threadIdx.x & 63;
    int n = blockIdx.x * 4 + w;
    int q = lane & 15, par = lane >> 4;   // 4 edges in parallel, lane covers chans 2q,2q+1
    const uint32* H2d = (const uint32*)H2b;
    float ad = a_dst[n];
    float ldn = 0.f, ax = 0.f, ay = 0.f;
    int beg = offsets[n], end = offsets[n + 1];
    for (int cbeg = beg; cbeg < end; cbeg += CAP) {
        int L = end - cbeg; if (L > CAP) L = CAP;
        for (int tI = lane; tI < L; tI += 64) {
            int s = srcIdx[cbeg + tI];
            sl[w][tI] = s;
            float e = a_src[s] + ad;
            e = e > 0.f ? e : NEG_SLOPE * e;
            float p = __expf(e);
            pl[w][tI] = p;
            ldn += p;
        }
        for (int j = 0; j < L; j += 4) {
            int jj = j + par;
            if (jj < L) {
                int s = sl[w][jj];
                float p = pl[w][jj];
                uint32 d = H2d[(size_t)s * 16 + q];
                ax += p * lo16(d);
                ay += p * hi16(d);
            }
        }
    }
#pragma unroll
    for (int o = 32; o; o >>= 1) ldn += __shfl_xor(ldn, o);
    ax += __shfl_xor(ax, 16); ax += __shfl_xor(ax, 32);
    ay += __shfl_xor(ay, 16); ay += __shfl_xor(ay, 32);
    if (lane < 16) {
        float2 bb = ((const float2*)b2)[q];
        float2 o;
        o.x = ax / ldn + bb.x;
        o.y = ay / ldn + bb.y;
        ((float2*)out)[(size_t)n * 16 + q] = o;
    }
}

// ---------------- launch ----------------

static inline size_t align256(size_t x) { return (x + 255) & ~size_t(255); }

extern "C" void kernel_launch(void* const* d_in, const int* in_sizes, int n_in,
                              void* d_out, int out_size, void* d_ws, size_t ws_size,
                              hipStream_t stream) {
    const float* x        = (const float*)d_in[0];
    const int*   ei       = (const int*)d_in[1];
    const float* W1       = (const float*)d_in[2];
    const float* att_src1 = (const float*)d_in[3];
    const float* att_dst1 = (const float*)d_in[4];
    const float* b1       = (const float*)d_in[5];
    const float* W2       = (const float*)d_in[6];
    const float* att_src2 = (const float*)d_in[7];
    const float* att_dst2 = (const float*)d_in[8];
    const float* b2       = (const float*)d_in[9];
    float* out = (float*)d_out;

    const int* e_src = ei;
    const int* e_dst = ei + EE;

    char* p = (char*)d_ws;
    ushort_t* H1b   = (ushort_t*)p; p += align256(sizeof(ushort_t) * (size_t)NN * D1);
    ushort_t* OUT1b = (ushort_t*)p; p += align256(sizeof(ushort_t) * (size_t)NN * D1);
    ushort_t* H2b   = (ushort_t*)p; p += align256(sizeof(ushort_t) * (size_t)NN * OUT_DIM);
    ushort_t* W1Tb  = (ushort_t*)p; p += align256(sizeof(ushort_t) * D1 * IN_DIM);
    ushort_t* W2Tb  = (ushort_t*)p; p += align256(sizeof(ushort_t) * D1 * OUT_DIM);
    float* AS1  = (float*)p; p += align256(sizeof(float) * NN * HEADS);
    float* AD1  = (float*)p; p += align256(sizeof(float) * NN * HEADS);
    float* AS2  = (float*)p; p += align256(sizeof(float) * NN);
    float* AD2  = (float*)p; p += align256(sizeof(float) * NN);
    int*   DEG  = (int*)p;   p += align256(sizeof(int) * NN);
    int*   OFF  = (int*)p;   p += align256(sizeof(int) * (NN + 1));
    int*   CUR  = (int*)p;   p += align256(sizeof(int) * NN);
    int*   BSUM = (int*)p;   p += align256(sizeof(int) * NBLK);
    int*   BPRE = (int*)p;   p += align256(sizeof(int) * NBLK);
    int*   SIDX = (int*)p;   p += align256(sizeof(int) * (EE + NN));

    // CSR build + weight prep
    w1t_kernel<<<dim3(D1 / 32, IN_DIM / 32), 256, 0, stream>>>(W1, W1Tb);
    w2t_kernel<<<48, 256, 0, stream>>>(W2, W2Tb);
    deg_init_kernel<<<(NN + 255) / 256, 256, 0, stream>>>(DEG);
    hist_kernel<<<(EE + 255) / 256, 256, 0, stream>>>(e_dst, DEG);
    scan1_kernel<<<NBLK, 256, 0, stream>>>(DEG, BSUM);
    scan2_kernel<<<1, 256, 0, stream>>>(BSUM, BPRE, OFF);
    scan3_kernel<<<NBLK, 256, 0, stream>>>(DEG, BPRE, OFF, CUR);
    scatter_kernel<<<(EE + NN + 255) / 256, 256, 0, stream>>>(e_src, e_dst, CUR, SIDX);

    // layer 1
    gemm1_kernel<<<(NN + G1_BM - 1) / G1_BM, 256, 0, stream>>>(x, W1Tb, H1b);
    avec1_kernel<<<NN / 4, 256, 0, stream>>>((const uint32*)H1b, att_src1, att_dst1, AS1, AD1);
    agg1_kernel<<<NN / 4, 256, 0, stream>>>((const uint32*)H1b, AS1, AD1, OFF, SIDX, b1, (uint32*)OUT1b);

    // layer 2
    gemm2_kernel<<<(NN + G2_ROWS - 1) / G2_ROWS, 256, 0, stream>>>(OUT1b, W2Tb, att_src2, att_dst2, H2b, AS2, AD2);
    agg2_kernel<<<NN / 4, 256, 0, stream>>>(H2b, AS2, AD2, OFF, SIDX, b2, out);
}

// Round 6
// 328.675 us; speedup vs baseline: 2.3056x; 1.0327x over previous
//
#include <hip/hip_runtime.h>
#include <hip/hip_bf16.h>

#define NN 50000
#define EE 800000
#define IN_DIM 256
#define HID 64
#define HEADS 6
#define D1 384            // HEADS*HID
#define OUT_DIM 32
#define NEG_SLOPE 0.2f
#define CAP 128           // edge chunk per node held in LDS
#define NBLK 196          // ceil(50000/256)

typedef unsigned int uint32;
typedef unsigned short ushort_t;
typedef short short8 __attribute__((ext_vector_type(8)));
typedef float f32x4 __attribute__((ext_vector_type(4)));
typedef ushort_t ushort8 __attribute__((ext_vector_type(8)));

__device__ __forceinline__ ushort_t f2bf(float f) {
    uint32 u = __builtin_bit_cast(uint32, f);
    u += 0x7fffu + ((u >> 16) & 1u);
    return (ushort_t)(u >> 16);
}
__device__ __forceinline__ float bf2f(ushort_t s) {
    uint32 u = ((uint32)s) << 16;
    return __builtin_bit_cast(float, u);
}
// dword d holds std channels (2d) in low half, (2d+1) in high half
__device__ __forceinline__ float lo16(uint32 d) { return __builtin_bit_cast(float, d << 16); }
__device__ __forceinline__ float hi16(uint32 d) { return __builtin_bit_cast(float, d & 0xffff0000u); }

// ---------------- CSR build ----------------

__global__ void hist_kernel(const int* __restrict__ dst, int* __restrict__ deg) {
    int i = blockIdx.x * 256 + threadIdx.x;
    if (i < EE) atomicAdd(&deg[dst[i]], 1);
}

// deg is read-side +1 (self-loop); DEG buffer is memset to 0 before hist.
__global__ __launch_bounds__(256) void scan1_kernel(const int* __restrict__ deg,
                                                    int* __restrict__ blockSums) {
    int t = threadIdx.x;
    int i = blockIdx.x * 256 + t;
    int v = (i < NN) ? (deg[i] + 1) : 0;
#pragma unroll
    for (int o = 32; o; o >>= 1) v += __shfl_xor(v, o);
    __shared__ int ws[4];
    if ((t & 63) == 0) ws[t >> 6] = v;
    __syncthreads();
    if (t == 0) blockSums[blockIdx.x] = ws[0] + ws[1] + ws[2] + ws[3];
}

__global__ __launch_bounds__(256) void scan2_kernel(const int* __restrict__ blockSums,
                                                    int* __restrict__ blockPrefix,
                                                    int* __restrict__ offsets) {
    int t = threadIdx.x;
    int lane = t & 63, w = t >> 6;
    int v = (t < NBLK) ? blockSums[t] : 0;
    int x = v;
#pragma unroll
    for (int o = 1; o < 64; o <<= 1) {
        int y = __shfl_up(x, o);
        if (lane >= o) x += y;
    }
    __shared__ int ws[4];
    if (lane == 63) ws[w] = x;
    __syncthreads();
    int wpre = 0;
#pragma unroll
    for (int k = 0; k < 4; ++k) if (k < w) wpre += ws[k];
    int incl = x + wpre;
    if (t < NBLK) blockPrefix[t] = incl - v;
    if (t == NBLK - 1) offsets[NN] = incl;   // total == EE+NN
}

__global__ __launch_bounds__(256) void scan3_kernel(const int* __restrict__ deg,
                                                    const int* __restrict__ blockPrefix,
                                                    int* __restrict__ offsets,
                                                    int* __restrict__ cursor) {
    int t = threadIdx.x;
    int i = blockIdx.x * 256 + t;
    int lane = t & 63, w = t >> 6;
    int v = (i < NN) ? (deg[i] + 1) : 0;
    int x = v;
#pragma unroll
    for (int o = 1; o < 64; o <<= 1) {
        int y = __shfl_up(x, o);
        if (lane >= o) x += y;
    }
    __shared__ int ws[4];
    if (lane == 63) ws[w] = x;
    __syncthreads();
    int wpre = 0;
#pragma unroll
    for (int k = 0; k < 4; ++k) if (k < w) wpre += ws[k];
    int excl = x + wpre - v + blockPrefix[blockIdx.x];
    if (i < NN) { offsets[i] = excl; cursor[i] = excl; }
}

__global__ void scatter_kernel(const int* __restrict__ src, const int* __restrict__ dst,
                               int* __restrict__ cursor, int* __restrict__ srcIdx) {
    int i = blockIdx.x * 256 + threadIdx.x;
    if (i >= EE + NN) return;
    int s, d;
    if (i < EE) { s = src[i]; d = dst[i]; }
    else        { s = i - EE; d = s; }
    int pos = atomicAdd(&cursor[d], 1);
    srcIdx[pos] = s;
}

// ---------------- weight prep ----------------

__global__ __launch_bounds__(256) void w1t_kernel(const float* __restrict__ W1,
                                                  ushort_t* __restrict__ W1Tb) {
    __shared__ float tile[32][33];
    int tx = threadIdx.x & 31, ty = threadIdx.x >> 5;   // 32x8
    int n0 = blockIdx.x * 32;
    int k0 = blockIdx.y * 32;
#pragma unroll
    for (int i = 0; i < 4; ++i)
        tile[ty + i * 8][tx] = W1[(k0 + ty + i * 8) * D1 + n0 + tx];
    __syncthreads();
#pragma unroll
    for (int i = 0; i < 4; ++i)
        W1Tb[(n0 + ty + i * 8) * IN_DIM + k0 + tx] = f2bf(tile[tx][ty + i * 8]);
}

// W2 [384][32] f32 -> W2Tb [32][384] bf16
__global__ __launch_bounds__(256) void w2t_kernel(const float* __restrict__ W2,
                                                  ushort_t* __restrict__ W2Tb) {
    int idx = blockIdx.x * 256 + threadIdx.x;   // 0..12287
    if (idx < D1 * OUT_DIM) {
        int k = idx >> 5, n = idx & 31;
        W2Tb[n * D1 + k] = f2bf(W2[idx]);
    }
}

// ---------------- GEMM1: H1b = bf16( x @ W1 ) via MFMA, fused a_src1/a_dst1 ----------------
// block tile: 64 rows x 384 cols (full N), K=256 in 4 steps of 64.
// wave wid covers cols wid*96..+96 (6 fn-blocks of 16). fn-block b = wid*6+fn
// belongs to head b>>2 (16 | 64). Epilogue computes per-head dots with att vecs.

#define G1_BM 64
#define G1_BK 64

__global__ __launch_bounds__(256) void gemm1_kernel(const float* __restrict__ A,
                                                    const ushort_t* __restrict__ Bt,
                                                    const float* __restrict__ att_src,
                                                    const float* __restrict__ att_dst,
                                                    ushort_t* __restrict__ Cb,
                                                    float* __restrict__ a_src1,
                                                    float* __restrict__ a_dst1) {
    __shared__ __align__(16) ushort_t As[G1_BM][G1_BK];   // 8 KB, 16B-chunk XOR swizzle
    __shared__ __align__(16) ushort_t Bs[D1][G1_BK];      // 48 KB, same swizzle
    __shared__ float redS[G1_BM][8];                      // 2 KB: [row][wid*2+headslot]
    __shared__ float redD[G1_BM][8];                      // 2 KB
    int t = threadIdx.x;
    int m0 = blockIdx.x * G1_BM;
    int wid = t >> 6, lane = t & 63;
    int lrow = lane & 15, lk = lane >> 4;
    f32x4 acc[4][6] = {};
    for (int k0 = 0; k0 < IN_DIM; k0 += G1_BK) {
        {
            int r = t >> 3, c = t & 7;
#pragma unroll
            for (int p = 0; p < 2; ++p) {
                int row = p * 32 + r;
                int gr = m0 + row;
                float4 v0 = make_float4(0.f, 0.f, 0.f, 0.f), v1 = v0;
                if (gr < NN) {
                    const float* g = &A[(size_t)gr * IN_DIM + k0 + c * 8];
                    v0 = *reinterpret_cast<const float4*>(g);
                    v1 = *reinterpret_cast<const float4*>(g + 4);
                }
                ushort8 u;
                u[0] = f2bf(v0.x); u[1] = f2bf(v0.y); u[2] = f2bf(v0.z); u[3] = f2bf(v0.w);
                u[4] = f2bf(v1.x); u[5] = f2bf(v1.y); u[6] = f2bf(v1.z); u[7] = f2bf(v1.w);
                *reinterpret_cast<ushort8*>(&As[row][(c ^ (row & 7)) * 8]) = u;
            }
        }
        {
            int r = t >> 3, c = t & 7;
#pragma unroll
            for (int p = 0; p < 12; ++p) {
                int row = p * 32 + r;
                ushort8 u = *reinterpret_cast<const ushort8*>(&Bt[row * IN_DIM + k0 + c * 8]);
                *reinterpret_cast<ushort8*>(&Bs[row][(c ^ (row & 7)) * 8]) = u;
            }
        }
        __syncthreads();
#pragma unroll
        for (int kk = 0; kk < G1_BK; kk += 32) {
            int ckb = (kk >> 3) + lk;
            short8 af[4];
#pragma unroll
            for (int fm = 0; fm < 4; ++fm) {
                int m = fm * 16 + lrow;
                af[fm] = *reinterpret_cast<const short8*>(&As[m][(ckb ^ (m & 7)) * 8]);
            }
#pragma unroll
            for (int fn = 0; fn < 6; ++fn) {
                int n = wid * 96 + fn * 16 + lrow;
                short8 bfv = *reinterpret_cast<const short8*>(&Bs[n][(ckb ^ (n & 7)) * 8]);
#pragma unroll
                for (int fm = 0; fm < 4; ++fm)
                    acc[fm][fn] = __builtin_amdgcn_mfma_f32_16x16x32_bf16(af[fm], bfv, acc[fm][fn], 0, 0, 0);
            }
        }
        __syncthreads();
    }
    // att values for this thread's 6 columns
    float atS[6], atD[6];
#pragma unroll
    for (int fn = 0; fn < 6; ++fn) {
        int col = wid * 96 + fn * 16 + lrow;
        atS[fn] = att_src[col];
        atD[fn] = att_dst[col];
    }
    int split = (wid & 1) ? 2 : 4;   // fn < split -> headslot 0, else headslot 1
    // epilogue: C/D layout col = lane&15, row = (lane>>4)*4 + reg
#pragma unroll
    for (int fm = 0; fm < 4; ++fm) {
#pragma unroll
        for (int r = 0; r < 4; ++r) {
            int rowl = fm * 16 + lk * 4 + r;
            int row = m0 + rowl;
            float vsA = 0.f, vsB = 0.f, vdA = 0.f, vdB = 0.f;
#pragma unroll
            for (int fn = 0; fn < 6; ++fn) {
                float v = acc[fm][fn][r];
                if (fn < split) { vsA += v * atS[fn]; vdA += v * atD[fn]; }
                else            { vsB += v * atS[fn]; vdB += v * atD[fn]; }
            }
#pragma unroll
            for (int o = 8; o; o >>= 1) {
                vsA += __shfl_xor(vsA, o); vsB += __shfl_xor(vsB, o);
                vdA += __shfl_xor(vdA, o); vdB += __shfl_xor(vdB, o);
            }
            if (lrow == 0) {
                redS[rowl][wid * 2 + 0] = vsA; redS[rowl][wid * 2 + 1] = vsB;
                redD[rowl][wid * 2 + 0] = vdA; redD[rowl][wid * 2 + 1] = vdB;
            }
            if (row < NN) {
#pragma unroll
                for (int fn = 0; fn < 6; ++fn) {
                    int col = wid * 96 + fn * 16 + lrow;
                    Cb[(size_t)row * D1 + col] = f2bf(acc[fm][fn][r]);
                }
            }
        }
    }
    __syncthreads();
    if (t < G1_BM) {
        int row = m0 + t;
        if (row < NN) {
            // head <- slot mapping: h0=s0; h1=s1+s2; h2=s3; h3=s4; h4=s5+s6; h5=s7
            float s0 = redS[t][0], s1 = redS[t][1] + redS[t][2], s2 = redS[t][3];
            float s3 = redS[t][4], s4 = redS[t][5] + redS[t][6], s5 = redS[t][7];
            float d0 = redD[t][0], d1 = redD[t][1] + redD[t][2], d2 = redD[t][3];
            float d3 = redD[t][4], d4 = redD[t][5] + redD[t][6], d5 = redD[t][7];
            float* ps = &a_src1[(size_t)row * HEADS];
            float* pd = &a_dst1[(size_t)row * HEADS];
            ps[0] = s0; ps[1] = s1; ps[2] = s2; ps[3] = s3; ps[4] = s4; ps[5] = s5;
            pd[0] = d0; pd[1] = d1; pd[2] = d2; pd[3] = d3; pd[4] = d4; pd[5] = d5;
        }
    }
}

// ---------------- layer-1 aggregation: exp-direct two-phase, deep-pipelined ----------------

__global__ __launch_bounds__(256, 4) void agg1_kernel(const uint32* __restrict__ H1d,
                                                      const float* __restrict__ a_src,
                                                      const float* __restrict__ a_dst,
                                                      const int* __restrict__ offsets,
                                                      const int* __restrict__ srcIdx,
                                                      const float* __restrict__ b1,
                                                      uint32* __restrict__ out1d) {
    __shared__ float pl[4][HEADS][CAP + 1];   // ~12.4 KB
    __shared__ int   sl[4][CAP];              // 2 KB
    int w = threadIdx.x >> 6, lane = threadIdx.x & 63;
    int hb = lane >> 5;
    int n = blockIdx.x * 4 + w;
    const float2* asv = (const float2*)a_src;
    float ad[HEADS];
#pragma unroll
    for (int h = 0; h < HEADS; ++h) ad[h] = a_dst[n * HEADS + h];
    float ldn[HEADS] = {0.f, 0.f, 0.f, 0.f, 0.f, 0.f};
    float acc[6] = {0.f, 0.f, 0.f, 0.f, 0.f, 0.f};
    int beg = offsets[n], end = offsets[n + 1];
    for (int cbeg = beg; cbeg < end; cbeg += CAP) {
        int L = end - cbeg; if (L > CAP) L = CAP;
        // ---- phase A: lanes over edges ----
        for (int tI = lane; tI < L; tI += 64) {
            int s = srcIdx[cbeg + tI];
            sl[w][tI] = s;
            float2 e0 = asv[s * 3 + 0];
            float2 e1 = asv[s * 3 + 1];
            float2 e2 = asv[s * 3 + 2];
            float ev[6] = {e0.x, e0.y, e1.x, e1.y, e2.x, e2.y};
#pragma unroll
            for (int h = 0; h < HEADS; ++h) {
                float e = ev[h] + ad[h];
                e = e > 0.f ? e : NEG_SLOPE * e;
                float p = __expf(e);
                pl[w][h][tI] = p;
                ldn[h] += p;
            }
        }
        // ---- phase B: lanes over dwords, 4 edges / 12 gathers in flight ----
        int j = 0;
        for (; j + 4 <= L; j += 4) {
            int s0 = sl[w][j], s1 = sl[w][j + 1], s2 = sl[w][j + 2], s3 = sl[w][j + 3];
            const uint32* h0 = H1d + (size_t)s0 * 192 + lane;
            const uint32* h1 = H1d + (size_t)s1 * 192 + lane;
            const uint32* h2 = H1d + (size_t)s2 * 192 + lane;
            const uint32* h3 = H1d + (size_t)s3 * 192 + lane;
            uint32 a0 = h0[0], a1 = h0[64], a2 = h0[128];
            uint32 b0 = h1[0], b1v_ = h1[64], b2 = h1[128];
            uint32 c0 = h2[0], c1 = h2[64], c2 = h2[128];
            uint32 d0 = h3[0], d1 = h3[64], d2 = h3[128];
            float p00 = pl[w][hb][j],     p01 = pl[w][2 + hb][j],     p02 = pl[w][4 + hb][j];
            float p10 = pl[w][hb][j + 1], p11 = pl[w][2 + hb][j + 1], p12 = pl[w][4 + hb][j + 1];
            float p20 = pl[w][hb][j + 2], p21 = pl[w][2 + hb][j + 2], p22 = pl[w][4 + hb][j + 2];
            float p30 = pl[w][hb][j + 3], p31 = pl[w][2 + hb][j + 3], p32 = pl[w][4 + hb][j + 3];
            acc[0] += p00 * lo16(a0); acc[1] += p00 * hi16(a0);
            acc[2] += p01 * lo16(a1); acc[3] += p01 * hi16(a1);
            acc[4] += p02 * lo16(a2); acc[5] += p02 * hi16(a2);
            acc[0] += p10 * lo16(b0); acc[1] += p10 * hi16(b0);
            acc[2] += p11 * lo16(b1v_); acc[3] += p11 * hi16(b1v_);
            acc[4] += p12 * lo16(b2); acc[5] += p12 * hi16(b2);
            acc[0] += p20 * lo16(c0); acc[1] += p20 * hi16(c0);
            acc[2] += p21 * lo16(c1); acc[3] += p21 * hi16(c1);
            acc[4] += p22 * lo16(c2); acc[5] += p22 * hi16(c2);
            acc[0] += p30 * lo16(d0); acc[1] += p30 * hi16(d0);
            acc[2] += p31 * lo16(d1); acc[3] += p31 * hi16(d1);
            acc[4] += p32 * lo16(d2); acc[5] += p32 * hi16(d2);
        }
        for (; j < L; ++j) {
            int s0 = sl[w][j];
            const uint32* h0 = H1d + (size_t)s0 * 192 + lane;
            uint32 x0 = h0[0], x1 = h0[64], x2 = h0[128];
            float p0 = pl[w][hb][j], p1 = pl[w][2 + hb][j], p2 = pl[w][4 + hb][j];
            acc[0] += p0 * lo16(x0); acc[1] += p0 * hi16(x0);
            acc[2] += p1 * lo16(x1); acc[3] += p1 * hi16(x1);
            acc[4] += p2 * lo16(x2); acc[5] += p2 * hi16(x2);
        }
    }
#pragma unroll
    for (int h = 0; h < HEADS; ++h) {
#pragma unroll
        for (int o = 32; o; o >>= 1) ldn[h] += __shfl_xor(ldn[h], o);
    }
    float dsel[3];
#pragma unroll
    for (int k = 0; k < 3; ++k) dsel[k] = hb ? ldn[2 * k + 1] : ldn[2 * k];
    const float2* b1v = (const float2*)b1;
#pragma unroll
    for (int k = 0; k < 3; ++k) {
        float2 bb = b1v[k * 64 + lane];
        float v0 = fmaxf(acc[2 * k]     / dsel[k] + bb.x, 0.f);
        float v1 = fmaxf(acc[2 * k + 1] / dsel[k] + bb.y, 0.f);
        out1d[(size_t)n * 192 + k * 64 + lane] = (uint32)f2bf(v0) | ((uint32)f2bf(v1) << 16);
    }
}

// ---------------- GEMM2 via MFMA (+ fused a_src2/a_dst2) ----------------

#define G2_ROWS 256

__global__ __launch_bounds__(256) void gemm2_kernel(const ushort_t* __restrict__ Xb,
                                                    const ushort_t* __restrict__ W2Tb,
                                                    const float* __restrict__ att_src2,
                                                    const float* __restrict__ att_dst2,
                                                    ushort_t* __restrict__ H2b,
                                                    float* __restrict__ a_src2,
                                                    float* __restrict__ a_dst2) {
    __shared__ __align__(16) ushort_t Ws[OUT_DIM][D1];     // 24 KB, swizzled per 64-span
    __shared__ __align__(16) ushort_t Xs[G2_ROWS][64];     // 32 KB, swizzled
    int t = threadIdx.x;
    int wid = t >> 6, lane = t & 63;
    int lrow = lane & 15, lk = lane >> 4;
    int m0 = blockIdx.x * G2_ROWS;
#pragma unroll
    for (int p = 0; p < 6; ++p) {
        int chunk = p * 256 + t;
        int nr = chunk / 48, c = chunk % 48;
        ushort8 u = *reinterpret_cast<const ushort8*>(&W2Tb[nr * D1 + c * 8]);
        int span = c >> 3, cc = c & 7;
        *reinterpret_cast<ushort8*>(&Ws[nr][(cc ^ (nr & 7)) * 8 + span * 64]) = u;
    }
    f32x4 acc[4][2] = {};
    for (int kc = 0; kc < 6; ++kc) {
        int k0 = kc * 64;
        {
            int r = t >> 3, c = t & 7;
#pragma unroll
            for (int p = 0; p < 8; ++p) {
                int row = p * 32 + r;
                int gr = m0 + row;
                ushort8 u = {0, 0, 0, 0, 0, 0, 0, 0};
                if (gr < NN) u = *reinterpret_cast<const ushort8*>(&Xb[(size_t)gr * D1 + k0 + c * 8]);
                *reinterpret_cast<ushort8*>(&Xs[row][(c ^ (row & 7)) * 8]) = u;
            }
        }
        __syncthreads();
#pragma unroll
        for (int kk = 0; kk < 64; kk += 32) {
            int ckb = (kk >> 3) + lk;
            short8 af[4];
#pragma unroll
            for (int fm = 0; fm < 4; ++fm) {
                int mm = wid * 64 + fm * 16 + lrow;
                af[fm] = *reinterpret_cast<const short8*>(&Xs[mm][(ckb ^ (mm & 7)) * 8]);
            }
#pragma unroll
            for (int fn = 0; fn < 2; ++fn) {
                int nn2 = fn * 16 + lrow;
                short8 bfv = *reinterpret_cast<const short8*>(&Ws[nn2][(ckb ^ (nn2 & 7)) * 8 + kc * 64]);
#pragma unroll
                for (int fm = 0; fm < 4; ++fm)
                    acc[fm][fn] = __builtin_amdgcn_mfma_f32_16x16x32_bf16(af[fm], bfv, acc[fm][fn], 0, 0, 0);
            }
        }
        __syncthreads();
    }
    float as2a = att_src2[lrow], as2b = att_src2[16 + lrow];
    float ad2a = att_dst2[lrow], ad2b = att_dst2[16 + lrow];
#pragma unroll
    for (int fm = 0; fm < 4; ++fm) {
#pragma unroll
        for (int r = 0; r < 4; ++r) {
            int row = m0 + wid * 64 + fm * 16 + lk * 4 + r;
            float h0 = acc[fm][0][r], h1 = acc[fm][1][r];
            float vs = h0 * as2a + h1 * as2b;
            float vd = h0 * ad2a + h1 * ad2b;
#pragma unroll
            for (int o = 8; o; o >>= 1) {
                vs += __shfl_xor(vs, o);
                vd += __shfl_xor(vd, o);
            }
            if (row < NN) {
                H2b[(size_t)row * OUT_DIM + lrow]      = f2bf(h0);
                H2b[(size_t)row * OUT_DIM + 16 + lrow] = f2bf(h1);
                if (lrow == 0) { a_src2[row] = vs; a_dst2[row] = vd; }
            }
        }
    }
}

// ---------------- layer-2 aggregation: exp-direct (+b2) -> d_out ----------------

__global__ __launch_bounds__(256, 4) void agg2_kernel(const ushort_t* __restrict__ H2b,
                                                      const float* __restrict__ a_src,
                                                      const float* __restrict__ a_dst,
                                                      const int* __restrict__ offsets,
                                                      const int* __restrict__ srcIdx,
                                                      const float* __restrict__ b2,
                                                      float* __restrict__ out) {
    __shared__ float pl[4][CAP];
    __shared__ int   sl[4][CAP];
    int w = threadIdx.x >> 6, lane = threadIdx.x & 63;
    int n = blockIdx.x * 4 + w;
    int q = lane & 15, par = lane >> 4;   // 4 edges in parallel, lane covers chans 2q,2q+1
    const uint32* H2d = (const uint32*)H2b;
    float ad = a_dst[n];
    float ldn = 0.f, ax = 0.f, ay = 0.f;
    int beg = offsets[n], end = offsets[n + 1];
    for (int cbeg = beg; cbeg < end; cbeg += CAP) {
        int L = end - cbeg; if (L > CAP) L = CAP;
        for (int tI = lane; tI < L; tI += 64) {
            int s = srcIdx[cbeg + tI];
            sl[w][tI] = s;
            float e = a_src[s] + ad;
            e = e > 0.f ? e : NEG_SLOPE * e;
            float p = __expf(e);
            pl[w][tI] = p;
            ldn += p;
        }
        int j = 0;
        for (; j + 8 <= L; j += 8) {
            int s0 = sl[w][j + par], s1 = sl[w][j + 4 + par];
            float p0 = pl[w][j + par], p1 = pl[w][j + 4 + par];
            uint32 d0 = H2d[(size_t)s0 * 16 + q];
            uint32 d1 = H2d[(size_t)s1 * 16 + q];
            ax += p0 * lo16(d0) + p1 * lo16(d1);
            ay += p0 * hi16(d0) + p1 * hi16(d1);
        }
        for (; j < L; j += 4) {
            int jj = j + par;
            if (jj < L) {
                int s = sl[w][jj];
                float p = pl[w][jj];
                uint32 d = H2d[(size_t)s * 16 + q];
                ax += p * lo16(d);
                ay += p * hi16(d);
            }
        }
    }
#pragma unroll
    for (int o = 32; o; o >>= 1) ldn += __shfl_xor(ldn, o);
    ax += __shfl_xor(ax, 16); ax += __shfl_xor(ax, 32);
    ay += __shfl_xor(ay, 16); ay += __shfl_xor(ay, 32);
    if (lane < 16) {
        float2 bb = ((const float2*)b2)[q];
        float2 o;
        o.x = ax / ldn + bb.x;
        o.y = ay / ldn + bb.y;
        ((float2*)out)[(size_t)n * 16 + q] = o;
    }
}

// ---------------- launch ----------------

static inline size_t align256(size_t x) { return (x + 255) & ~size_t(255); }

extern "C" void kernel_launch(void* const* d_in, const int* in_sizes, int n_in,
                              void* d_out, int out_size, void* d_ws, size_t ws_size,
                              hipStream_t stream) {
    const float* x        = (const float*)d_in[0];
    const int*   ei       = (const int*)d_in[1];
    const float* W1       = (const float*)d_in[2];
    const float* att_src1 = (const float*)d_in[3];
    const float* att_dst1 = (const float*)d_in[4];
    const float* b1       = (const float*)d_in[5];
    const float* W2       = (const float*)d_in[6];
    const float* att_src2 = (const float*)d_in[7];
    const float* att_dst2 = (const float*)d_in[8];
    const float* b2       = (const float*)d_in[9];
    float* out = (float*)d_out;

    const int* e_src = ei;
    const int* e_dst = ei + EE;

    char* p = (char*)d_ws;
    ushort_t* H1b   = (ushort_t*)p; p += align256(sizeof(ushort_t) * (size_t)NN * D1);
    ushort_t* OUT1b = (ushort_t*)p; p += align256(sizeof(ushort_t) * (size_t)NN * D1);
    ushort_t* H2b   = (ushort_t*)p; p += align256(sizeof(ushort_t) * (size_t)NN * OUT_DIM);
    ushort_t* W1Tb  = (ushort_t*)p; p += align256(sizeof(ushort_t) * D1 * IN_DIM);
    ushort_t* W2Tb  = (ushort_t*)p; p += align256(sizeof(ushort_t) * D1 * OUT_DIM);
    float* AS1  = (float*)p; p += align256(sizeof(float) * NN * HEADS);
    float* AD1  = (float*)p; p += align256(sizeof(float) * NN * HEADS);
    float* AS2  = (float*)p; p += align256(sizeof(float) * NN);
    float* AD2  = (float*)p; p += align256(sizeof(float) * NN);
    int*   DEG  = (int*)p;   p += align256(sizeof(int) * NN);
    int*   OFF  = (int*)p;   p += align256(sizeof(int) * (NN + 1));
    int*   CUR  = (int*)p;   p += align256(sizeof(int) * NN);
    int*   BSUM = (int*)p;   p += align256(sizeof(int) * NBLK);
    int*   BPRE = (int*)p;   p += align256(sizeof(int) * NBLK);
    int*   SIDX = (int*)p;   p += align256(sizeof(int) * (EE + NN));

    // CSR build + weight prep
    hipMemsetAsync(DEG, 0, sizeof(int) * NN, stream);
    w1t_kernel<<<dim3(D1 / 32, IN_DIM / 32), 256, 0, stream>>>(W1, W1Tb);
    w2t_kernel<<<48, 256, 0, stream>>>(W2, W2Tb);
    hist_kernel<<<(EE + 255) / 256, 256, 0, stream>>>(e_dst, DEG);
    scan1_kernel<<<NBLK, 256, 0, stream>>>(DEG, BSUM);
    scan2_kernel<<<1, 256, 0, stream>>>(BSUM, BPRE, OFF);
    scan3_kernel<<<NBLK, 256, 0, stream>>>(DEG, BPRE, OFF, CUR);
    scatter_kernel<<<(EE + NN + 255) / 256, 256, 0, stream>>>(e_src, e_dst, CUR, SIDX);

    // layer 1
    gemm1_kernel<<<(NN + G1_BM - 1) / G1_BM, 256, 0, stream>>>(x, W1Tb, att_src1, att_dst1, H1b, AS1, AD1);
    agg1_kernel<<<NN / 4, 256, 0, stream>>>((const uint32*)H1b, AS1, AD1, OFF, SIDX, b1, (uint32*)OUT1b);

    // layer 2
    gemm2_kernel<<<(NN + G2_ROWS - 1) / G2_ROWS, 256, 0, stream>>>(OUT1b, W2Tb, att_src2, att_dst2, H2b, AS2, AD2);
    agg2_kernel<<<NN / 4, 256, 0, stream>>>(H2b, AS2, AD2, OFF, SIDX, b2, out);
}

// Round 8
// 316.467 us; speedup vs baseline: 2.3945x; 1.0386x over previous
//
#include <hip/hip_runtime.h>
#include <hip/hip_bf16.h>

#define NN 50000
#define EE 800000
#define IN_DIM 256
#define HID 64
#define HEADS 6
#define D1 384            // HEADS*HID
#define OUT_DIM 32
#define NEG_SLOPE 0.2f
#define CAP 128           // edge chunk per node held in LDS
#define NBLK 196          // ceil(50000/256)

typedef unsigned int uint32;
typedef unsigned short ushort_t;
typedef short short8 __attribute__((ext_vector_type(8)));
typedef float f32x4 __attribute__((ext_vector_type(4)));
typedef float f32x2 __attribute__((ext_vector_type(2)));
typedef ushort_t ushort8 __attribute__((ext_vector_type(8)));

__device__ __forceinline__ ushort_t f2bf(float f) {
    uint32 u = __builtin_bit_cast(uint32, f);
    u += 0x7fffu + ((u >> 16) & 1u);
    return (ushort_t)(u >> 16);
}
__device__ __forceinline__ float bf2f(ushort_t s) {
    uint32 u = ((uint32)s) << 16;
    return __builtin_bit_cast(float, u);
}
// dword d holds std channels (2d) in low half, (2d+1) in high half
__device__ __forceinline__ float lo16(uint32 d) { return __builtin_bit_cast(float, d << 16); }
__device__ __forceinline__ float hi16(uint32 d) { return __builtin_bit_cast(float, d & 0xffff0000u); }

// ---------------- CSR build ----------------

__global__ void hist_kernel(const int* __restrict__ dst, int* __restrict__ deg) {
    int i = blockIdx.x * 256 + threadIdx.x;
    if (i < EE) atomicAdd(&deg[dst[i]], 1);
}

// deg is read-side +1 (self-loop); DEG buffer is memset to 0 before hist.
__global__ __launch_bounds__(256) void scan1_kernel(const int* __restrict__ deg,
                                                    int* __restrict__ blockSums) {
    int t = threadIdx.x;
    int i = blockIdx.x * 256 + t;
    int v = (i < NN) ? (deg[i] + 1) : 0;
#pragma unroll
    for (int o = 32; o; o >>= 1) v += __shfl_xor(v, o);
    __shared__ int ws[4];
    if ((t & 63) == 0) ws[t >> 6] = v;
    __syncthreads();
    if (t == 0) blockSums[blockIdx.x] = ws[0] + ws[1] + ws[2] + ws[3];
}

__global__ __launch_bounds__(256) void scan2_kernel(const int* __restrict__ blockSums,
                                                    int* __restrict__ blockPrefix,
                                                    int* __restrict__ offsets) {
    int t = threadIdx.x;
    int lane = t & 63, w = t >> 6;
    int v = (t < NBLK) ? blockSums[t] : 0;
    int x = v;
#pragma unroll
    for (int o = 1; o < 64; o <<= 1) {
        int y = __shfl_up(x, o);
        if (lane >= o) x += y;
    }
    __shared__ int ws[4];
    if (lane == 63) ws[w] = x;
    __syncthreads();
    int wpre = 0;
#pragma unroll
    for (int k = 0; k < 4; ++k) if (k < w) wpre += ws[k];
    int incl = x + wpre;
    if (t < NBLK) blockPrefix[t] = incl - v;
    if (t == NBLK - 1) offsets[NN] = incl;   // total == EE+NN
}

__global__ __launch_bounds__(256) void scan3_kernel(const int* __restrict__ deg,
                                                    const int* __restrict__ blockPrefix,
                                                    int* __restrict__ offsets,
                                                    int* __restrict__ cursor) {
    int t = threadIdx.x;
    int i = blockIdx.x * 256 + t;
    int lane = t & 63, w = t >> 6;
    int v = (i < NN) ? (deg[i] + 1) : 0;
    int x = v;
#pragma unroll
    for (int o = 1; o < 64; o <<= 1) {
        int y = __shfl_up(x, o);
        if (lane >= o) x += y;
    }
    __shared__ int ws[4];
    if (lane == 63) ws[w] = x;
    __syncthreads();
    int wpre = 0;
#pragma unroll
    for (int k = 0; k < 4; ++k) if (k < w) wpre += ws[k];
    int excl = x + wpre - v + blockPrefix[blockIdx.x];
    if (i < NN) { offsets[i] = excl; cursor[i] = excl; }
}

__global__ void scatter_kernel(const int* __restrict__ src, const int* __restrict__ dst,
                               int* __restrict__ cursor, int* __restrict__ srcIdx) {
    int i = blockIdx.x * 256 + threadIdx.x;
    if (i >= EE + NN) return;
    int s, d;
    if (i < EE) { s = src[i]; d = dst[i]; }
    else        { s = i - EE; d = s; }
    int pos = atomicAdd(&cursor[d], 1);
    srcIdx[pos] = s;
}

// ---------------- weight prep ----------------

__global__ __launch_bounds__(256) void w1t_kernel(const float* __restrict__ W1,
                                                  ushort_t* __restrict__ W1Tb) {
    __shared__ float tile[32][33];
    int tx = threadIdx.x & 31, ty = threadIdx.x >> 5;   // 32x8
    int n0 = blockIdx.x * 32;
    int k0 = blockIdx.y * 32;
#pragma unroll
    for (int i = 0; i < 4; ++i)
        tile[ty + i * 8][tx] = W1[(k0 + ty + i * 8) * D1 + n0 + tx];
    __syncthreads();
#pragma unroll
    for (int i = 0; i < 4; ++i)
        W1Tb[(n0 + ty + i * 8) * IN_DIM + k0 + tx] = f2bf(tile[tx][ty + i * 8]);
}

// W2 [384][32] f32 -> W2Tb [32][384] bf16
__global__ __launch_bounds__(256) void w2t_kernel(const float* __restrict__ W2,
                                                  ushort_t* __restrict__ W2Tb) {
    int idx = blockIdx.x * 256 + threadIdx.x;   // 0..12287
    if (idx < D1 * OUT_DIM) {
        int k = idx >> 5, n = idx & 31;
        W2Tb[n * D1 + k] = f2bf(W2[idx]);
    }
}

// ---------------- GEMM1: H1b = bf16( x @ W1 ) via MFMA, fused a_src1/a_dst1 ----------------
// 128-row x 384-col block tile, 512 threads = 8 waves: rg=wid>>2 (row half), cg=wid&3 (96-col group).
// K=256 in 4 steps of 64.

#define G1_BM 128
#define G1_BK 64

__global__ __launch_bounds__(512) void gemm1_kernel(const float* __restrict__ A,
                                                    const ushort_t* __restrict__ Bt,
                                                    const float* __restrict__ att_src,
                                                    const float* __restrict__ att_dst,
                                                    ushort_t* __restrict__ Cb,
                                                    float* __restrict__ a_src1,
                                                    float* __restrict__ a_dst1) {
    __shared__ __align__(16) ushort_t As[G1_BM][G1_BK];   // 16 KB, 16B-chunk XOR swizzle
    __shared__ __align__(16) ushort_t Bs[D1][G1_BK];      // 48 KB, same swizzle
    __shared__ float redS[G1_BM][8];                      // 4 KB: [row][cg*2+headslot]
    __shared__ float redD[G1_BM][8];                      // 4 KB
    int t = threadIdx.x;
    int m0 = blockIdx.x * G1_BM;
    int wid = t >> 6, lane = t & 63;
    int rg = wid >> 2, cg = wid & 3;
    int lrow = lane & 15, lk = lane >> 4;
    f32x4 acc[4][6] = {};
    for (int k0 = 0; k0 < IN_DIM; k0 += G1_BK) {
        // stage A (f32 -> bf16): 128 rows x 8 chunks(16B) = 1024 chunks, 2/thread
        {
            int r = t >> 3, c = t & 7;
#pragma unroll
            for (int p = 0; p < 2; ++p) {
                int row = p * 64 + r;
                int gr = m0 + row;
                float4 v0 = make_float4(0.f, 0.f, 0.f, 0.f), v1 = v0;
                if (gr < NN) {
                    const float* g = &A[(size_t)gr * IN_DIM + k0 + c * 8];
                    v0 = *reinterpret_cast<const float4*>(g);
                    v1 = *reinterpret_cast<const float4*>(g + 4);
                }
                ushort8 u;
                u[0] = f2bf(v0.x); u[1] = f2bf(v0.y); u[2] = f2bf(v0.z); u[3] = f2bf(v0.w);
                u[4] = f2bf(v1.x); u[5] = f2bf(v1.y); u[6] = f2bf(v1.z); u[7] = f2bf(v1.w);
                *reinterpret_cast<ushort8*>(&As[row][(c ^ (row & 7)) * 8]) = u;
            }
        }
        // stage B: 384 rows x 8 chunks = 3072 chunks, 6/thread
        {
            int r = t >> 3, c = t & 7;
#pragma unroll
            for (int p = 0; p < 6; ++p) {
                int row = p * 64 + r;
                ushort8 u = *reinterpret_cast<const ushort8*>(&Bt[row * IN_DIM + k0 + c * 8]);
                *reinterpret_cast<ushort8*>(&Bs[row][(c ^ (row & 7)) * 8]) = u;
            }
        }
        __syncthreads();
#pragma unroll
        for (int kk = 0; kk < G1_BK; kk += 32) {
            int ckb = (kk >> 3) + lk;
            short8 af[4];
#pragma unroll
            for (int fm = 0; fm < 4; ++fm) {
                int m = rg * 64 + fm * 16 + lrow;
                af[fm] = *reinterpret_cast<const short8*>(&As[m][(ckb ^ (m & 7)) * 8]);
            }
#pragma unroll
            for (int fn = 0; fn < 6; ++fn) {
                int n = cg * 96 + fn * 16 + lrow;
                short8 bfv = *reinterpret_cast<const short8*>(&Bs[n][(ckb ^ (n & 7)) * 8]);
#pragma unroll
                for (int fm = 0; fm < 4; ++fm)
                    acc[fm][fn] = __builtin_amdgcn_mfma_f32_16x16x32_bf16(af[fm], bfv, acc[fm][fn], 0, 0, 0);
            }
        }
        __syncthreads();
    }
    // att values for this thread's 6 columns
    float atS[6], atD[6];
#pragma unroll
    for (int fn = 0; fn < 6; ++fn) {
        int col = cg * 96 + fn * 16 + lrow;
        atS[fn] = att_src[col];
        atD[fn] = att_dst[col];
    }
    int split = (cg & 1) ? 2 : 4;   // fn < split -> headslot 0, else headslot 1
    // epilogue: C/D layout col = lane&15, row = (lane>>4)*4 + reg
#pragma unroll
    for (int fm = 0; fm < 4; ++fm) {
#pragma unroll
        for (int r = 0; r < 4; ++r) {
            int rowl = rg * 64 + fm * 16 + lk * 4 + r;
            int row = m0 + rowl;
            float vsA = 0.f, vsB = 0.f, vdA = 0.f, vdB = 0.f;
#pragma unroll
            for (int fn = 0; fn < 6; ++fn) {
                float v = acc[fm][fn][r];
                if (fn < split) { vsA += v * atS[fn]; vdA += v * atD[fn]; }
                else            { vsB += v * atS[fn]; vdB += v * atD[fn]; }
            }
#pragma unroll
            for (int o = 8; o; o >>= 1) {
                vsA += __shfl_xor(vsA, o); vsB += __shfl_xor(vsB, o);
                vdA += __shfl_xor(vdA, o); vdB += __shfl_xor(vdB, o);
            }
            if (lrow == 0) {
                redS[rowl][cg * 2 + 0] = vsA; redS[rowl][cg * 2 + 1] = vsB;
                redD[rowl][cg * 2 + 0] = vdA; redD[rowl][cg * 2 + 1] = vdB;
            }
            if (row < NN) {
#pragma unroll
                for (int fn = 0; fn < 6; ++fn) {
                    int col = cg * 96 + fn * 16 + lrow;
                    Cb[(size_t)row * D1 + col] = f2bf(acc[fm][fn][r]);
                }
            }
        }
    }
    __syncthreads();
    if (t < G1_BM) {
        int row = m0 + t;
        if (row < NN) {
            // head <- slot mapping: h0=s0; h1=s1+s2; h2=s3; h3=s4; h4=s5+s6; h5=s7
            float s0 = redS[t][0], s1 = redS[t][1] + redS[t][2], s2 = redS[t][3];
            float s3 = redS[t][4], s4 = redS[t][5] + redS[t][6], s5 = redS[t][7];
            float d0 = redD[t][0], d1 = redD[t][1] + redD[t][2], d2 = redD[t][3];
            float d3 = redD[t][4], d4 = redD[t][5] + redD[t][6], d5 = redD[t][7];
            float* ps = &a_src1[(size_t)row * HEADS];
            float* pd = &a_dst1[(size_t)row * HEADS];
            ps[0] = s0; ps[1] = s1; ps[2] = s2; ps[3] = s3; ps[4] = s4; ps[5] = s5;
            pd[0] = d0; pd[1] = d1; pd[2] = d2; pd[3] = d3; pd[4] = d4; pd[5] = d5;
        }
    }
}

// ---------------- layer-1 aggregation: exp-direct two-phase, deep-pipelined ----------------

__global__ __launch_bounds__(256, 4) void agg1_kernel(const uint32* __restrict__ H1d,
                                                      const float* __restrict__ a_src,
                                                      const float* __restrict__ a_dst,
                                                      const int* __restrict__ offsets,
                                                      const int* __restrict__ srcIdx,
                                                      const float* __restrict__ b1,
                                                      uint32* __restrict__ out1d) {
    __shared__ float pl[4][HEADS][CAP + 1];   // ~12.4 KB
    __shared__ int   sl[4][CAP];              // 2 KB
    int w = threadIdx.x >> 6, lane = threadIdx.x & 63;
    int hb = lane >> 5;
    int n = blockIdx.x * 4 + w;
    const float2* asv = (const float2*)a_src;
    float ad[HEADS];
#pragma unroll
    for (int h = 0; h < HEADS; ++h) ad[h] = a_dst[n * HEADS + h];
    float ldn[HEADS] = {0.f, 0.f, 0.f, 0.f, 0.f, 0.f};
    float acc[6] = {0.f, 0.f, 0.f, 0.f, 0.f, 0.f};
    int beg = offsets[n], end = offsets[n + 1];
    for (int cbeg = beg; cbeg < end; cbeg += CAP) {
        int L = end - cbeg; if (L > CAP) L = CAP;
        // ---- phase A: lanes over edges ----
        for (int tI = lane; tI < L; tI += 64) {
            int s = srcIdx[cbeg + tI];
            sl[w][tI] = s;
            float2 e0 = asv[s * 3 + 0];
            float2 e1 = asv[s * 3 + 1];
            float2 e2 = asv[s * 3 + 2];
            float ev[6] = {e0.x, e0.y, e1.x, e1.y, e2.x, e2.y};
#pragma unroll
            for (int h = 0; h < HEADS; ++h) {
                float e = ev[h] + ad[h];
                e = e > 0.f ? e : NEG_SLOPE * e;
                float p = __expf(e);
                pl[w][h][tI] = p;
                ldn[h] += p;
            }
        }
        // ---- phase B: lanes over dwords, 4 edges / 12 gathers in flight ----
        int j = 0;
        for (; j + 4 <= L; j += 4) {
            int s0 = sl[w][j], s1 = sl[w][j + 1], s2 = sl[w][j + 2], s3 = sl[w][j + 3];
            const uint32* h0 = H1d + (size_t)s0 * 192 + lane;
            const uint32* h1 = H1d + (size_t)s1 * 192 + lane;
            const uint32* h2 = H1d + (size_t)s2 * 192 + lane;
            const uint32* h3 = H1d + (size_t)s3 * 192 + lane;
            uint32 a0 = h0[0], a1 = h0[64], a2 = h0[128];
            uint32 b0 = h1[0], b1v_ = h1[64], b2 = h1[128];
            uint32 c0 = h2[0], c1 = h2[64], c2 = h2[128];
            uint32 d0 = h3[0], d1 = h3[64], d2 = h3[128];
            float p00 = pl[w][hb][j],     p01 = pl[w][2 + hb][j],     p02 = pl[w][4 + hb][j];
            float p10 = pl[w][hb][j + 1], p11 = pl[w][2 + hb][j + 1], p12 = pl[w][4 + hb][j + 1];
            float p20 = pl[w][hb][j + 2], p21 = pl[w][2 + hb][j + 2], p22 = pl[w][4 + hb][j + 2];
            float p30 = pl[w][hb][j + 3], p31 = pl[w][2 + hb][j + 3], p32 = pl[w][4 + hb][j + 3];
            acc[0] += p00 * lo16(a0); acc[1] += p00 * hi16(a0);
            acc[2] += p01 * lo16(a1); acc[3] += p01 * hi16(a1);
            acc[4] += p02 * lo16(a2); acc[5] += p02 * hi16(a2);
            acc[0] += p10 * lo16(b0); acc[1] += p10 * hi16(b0);
            acc[2] += p11 * lo16(b1v_); acc[3] += p11 * hi16(b1v_);
            acc[4] += p12 * lo16(b2); acc[5] += p12 * hi16(b2);
            acc[0] += p20 * lo16(c0); acc[1] += p20 * hi16(c0);
            acc[2] += p21 * lo16(c1); acc[3] += p21 * hi16(c1);
            acc[4] += p22 * lo16(c2); acc[5] += p22 * hi16(c2);
            acc[0] += p30 * lo16(d0); acc[1] += p30 * hi16(d0);
            acc[2] += p31 * lo16(d1); acc[3] += p31 * hi16(d1);
            acc[4] += p32 * lo16(d2); acc[5] += p32 * hi16(d2);
        }
        for (; j < L; ++j) {
            int s0 = sl[w][j];
            const uint32* h0 = H1d + (size_t)s0 * 192 + lane;
            uint32 x0 = h0[0], x1 = h0[64], x2 = h0[128];
            float p0 = pl[w][hb][j], p1 = pl[w][2 + hb][j], p2 = pl[w][4 + hb][j];
            acc[0] += p0 * lo16(x0); acc[1] += p0 * hi16(x0);
            acc[2] += p1 * lo16(x1); acc[3] += p1 * hi16(x1);
            acc[4] += p2 * lo16(x2); acc[5] += p2 * hi16(x2);
        }
    }
#pragma unroll
    for (int h = 0; h < HEADS; ++h) {
#pragma unroll
        for (int o = 32; o; o >>= 1) ldn[h] += __shfl_xor(ldn[h], o);
    }
    float dsel[3];
#pragma unroll
    for (int k = 0; k < 3; ++k) dsel[k] = hb ? ldn[2 * k + 1] : ldn[2 * k];
    const float2* b1v = (const float2*)b1;
#pragma unroll
    for (int k = 0; k < 3; ++k) {
        float2 bb = b1v[k * 64 + lane];
        float v0 = fmaxf(acc[2 * k]     / dsel[k] + bb.x, 0.f);
        float v1 = fmaxf(acc[2 * k + 1] / dsel[k] + bb.y, 0.f);
        uint32 pk = (uint32)f2bf(v0) | ((uint32)f2bf(v1) << 16);
        __builtin_nontemporal_store(pk, &out1d[(size_t)n * 192 + k * 64 + lane]);
    }
}

// ---------------- GEMM2 via MFMA (+ fused a_src2/a_dst2) ----------------

#define G2_ROWS 256

__global__ __launch_bounds__(256) void gemm2_kernel(const ushort_t* __restrict__ Xb,
                                                    const ushort_t* __restrict__ W2Tb,
                                                    const float* __restrict__ att_src2,
                                                    const float* __restrict__ att_dst2,
                                                    ushort_t* __restrict__ H2b,
                                                    float* __restrict__ a_src2,
                                                    float* __restrict__ a_dst2) {
    __shared__ __align__(16) ushort_t Ws[OUT_DIM][D1];     // 24 KB, swizzled per 64-span
    __shared__ __align__(16) ushort_t Xs[G2_ROWS][64];     // 32 KB, swizzled
    int t = threadIdx.x;
    int wid = t >> 6, lane = t & 63;
    int lrow = lane & 15, lk = lane >> 4;
    int m0 = blockIdx.x * G2_ROWS;
#pragma unroll
    for (int p = 0; p < 6; ++p) {
        int chunk = p * 256 + t;
        int nr = chunk / 48, c = chunk % 48;
        ushort8 u = *reinterpret_cast<const ushort8*>(&W2Tb[nr * D1 + c * 8]);
        int span = c >> 3, cc = c & 7;
        *reinterpret_cast<ushort8*>(&Ws[nr][(cc ^ (nr & 7)) * 8 + span * 64]) = u;
    }
    f32x4 acc[4][2] = {};
    for (int kc = 0; kc < 6; ++kc) {
        int k0 = kc * 64;
        {
            int r = t >> 3, c = t & 7;
#pragma unroll
            for (int p = 0; p < 8; ++p) {
                int row = p * 32 + r;
                int gr = m0 + row;
                ushort8 u = {0, 0, 0, 0, 0, 0, 0, 0};
                if (gr < NN) u = *reinterpret_cast<const ushort8*>(&Xb[(size_t)gr * D1 + k0 + c * 8]);
                *reinterpret_cast<ushort8*>(&Xs[row][(c ^ (row & 7)) * 8]) = u;
            }
        }
        __syncthreads();
#pragma unroll
        for (int kk = 0; kk < 64; kk += 32) {
            int ckb = (kk >> 3) + lk;
            short8 af[4];
#pragma unroll
            for (int fm = 0; fm < 4; ++fm) {
                int mm = wid * 64 + fm * 16 + lrow;
                af[fm] = *reinterpret_cast<const short8*>(&Xs[mm][(ckb ^ (mm & 7)) * 8]);
            }
#pragma unroll
            for (int fn = 0; fn < 2; ++fn) {
                int nn2 = fn * 16 + lrow;
                short8 bfv = *reinterpret_cast<const short8*>(&Ws[nn2][(ckb ^ (nn2 & 7)) * 8 + kc * 64]);
#pragma unroll
                for (int fm = 0; fm < 4; ++fm)
                    acc[fm][fn] = __builtin_amdgcn_mfma_f32_16x16x32_bf16(af[fm], bfv, acc[fm][fn], 0, 0, 0);
            }
        }
        __syncthreads();
    }
    float as2a = att_src2[lrow], as2b = att_src2[16 + lrow];
    float ad2a = att_dst2[lrow], ad2b = att_dst2[16 + lrow];
#pragma unroll
    for (int fm = 0; fm < 4; ++fm) {
#pragma unroll
        for (int r = 0; r < 4; ++r) {
            int row = m0 + wid * 64 + fm * 16 + lk * 4 + r;
            float h0 = acc[fm][0][r], h1 = acc[fm][1][r];
            float vs = h0 * as2a + h1 * as2b;
            float vd = h0 * ad2a + h1 * ad2b;
#pragma unroll
            for (int o = 8; o; o >>= 1) {
                vs += __shfl_xor(vs, o);
                vd += __shfl_xor(vd, o);
            }
            if (row < NN) {
                H2b[(size_t)row * OUT_DIM + lrow]      = f2bf(h0);
                H2b[(size_t)row * OUT_DIM + 16 + lrow] = f2bf(h1);
                if (lrow == 0) { a_src2[row] = vs; a_dst2[row] = vd; }
            }
        }
    }
}

// ---------------- layer-2 aggregation: exp-direct (+b2) -> d_out ----------------

__global__ __launch_bounds__(256, 4) void agg2_kernel(const ushort_t* __restrict__ H2b,
                                                      const float* __restrict__ a_src,
                                                      const float* __restrict__ a_dst,
                                                      const int* __restrict__ offsets,
                                                      const int* __restrict__ srcIdx,
                                                      const float* __restrict__ b2,
                                                      float* __restrict__ out) {
    __shared__ float pl[4][CAP];
    __shared__ int   sl[4][CAP];
    int w = threadIdx.x >> 6, lane = threadIdx.x & 63;
    int n = blockIdx.x * 4 + w;
    int q = lane & 15, par = lane >> 4;   // 4 edges in parallel, lane covers chans 2q,2q+1
    const uint32* H2d = (const uint32*)H2b;
    float ad = a_dst[n];
    float ldn = 0.f, ax = 0.f, ay = 0.f;
    int beg = offsets[n], end = offsets[n + 1];
    for (int cbeg = beg; cbeg < end; cbeg += CAP) {
        int L = end - cbeg; if (L > CAP) L = CAP;
        for (int tI = lane; tI < L; tI += 64) {
            int s = srcIdx[cbeg + tI];
            sl[w][tI] = s;
            float e = a_src[s] + ad;
            e = e > 0.f ? e : NEG_SLOPE * e;
            float p = __expf(e);
            pl[w][tI] = p;
            ldn += p;
        }
        int j = 0;
        for (; j + 8 <= L; j += 8) {
            int s0 = sl[w][j + par], s1 = sl[w][j + 4 + par];
            float p0 = pl[w][j + par], p1 = pl[w][j + 4 + par];
            uint32 d0 = H2d[(size_t)s0 * 16 + q];
            uint32 d1 = H2d[(size_t)s1 * 16 + q];
            ax += p0 * lo16(d0) + p1 * lo16(d1);
            ay += p0 * hi16(d0) + p1 * hi16(d1);
        }
        for (; j < L; j += 4) {
            int jj = j + par;
            if (jj < L) {
                int s = sl[w][jj];
                float p = pl[w][jj];
                uint32 d = H2d[(size_t)s * 16 + q];
                ax += p * lo16(d);
                ay += p * hi16(d);
            }
        }
    }
#pragma unroll
    for (int o = 32; o; o >>= 1) ldn += __shfl_xor(ldn, o);
    ax += __shfl_xor(ax, 16); ax += __shfl_xor(ax, 32);
    ay += __shfl_xor(ay, 16); ay += __shfl_xor(ay, 32);
    if (lane < 16) {
        float2 bb = ((const float2*)b2)[q];
        f32x2 o;
        o[0] = ax / ldn + bb.x;
        o[1] = ay / ldn + bb.y;
        __builtin_nontemporal_store(o, (f32x2*)&out[(size_t)n * 32 + q * 2]);
    }
}

// ---------------- launch ----------------

static inline size_t align256(size_t x) { return (x + 255) & ~size_t(255); }

extern "C" void kernel_launch(void* const* d_in, const int* in_sizes, int n_in,
                              void* d_out, int out_size, void* d_ws, size_t ws_size,
                              hipStream_t stream) {
    const float* x        = (const float*)d_in[0];
    const int*   ei       = (const int*)d_in[1];
    const float* W1       = (const float*)d_in[2];
    const float* att_src1 = (const float*)d_in[3];
    const float* att_dst1 = (const float*)d_in[4];
    const float* b1       = (const float*)d_in[5];
    const float* W2       = (const float*)d_in[6];
    const float* att_src2 = (const float*)d_in[7];
    const float* att_dst2 = (const float*)d_in[8];
    const float* b2       = (const float*)d_in[9];
    float* out = (float*)d_out;

    const int* e_src = ei;
    const int* e_dst = ei + EE;

    char* p = (char*)d_ws;
    ushort_t* H1b   = (ushort_t*)p; p += align256(sizeof(ushort_t) * (size_t)NN * D1);
    ushort_t* OUT1b = (ushort_t*)p; p += align256(sizeof(ushort_t) * (size_t)NN * D1);
    ushort_t* H2b   = (ushort_t*)p; p += align256(sizeof(ushort_t) * (size_t)NN * OUT_DIM);
    ushort_t* W1Tb  = (ushort_t*)p; p += align256(sizeof(ushort_t) * D1 * IN_DIM);
    ushort_t* W2Tb  = (ushort_t*)p; p += align256(sizeof(ushort_t) * D1 * OUT_DIM);
    float* AS1  = (float*)p; p += align256(sizeof(float) * NN * HEADS);
    float* AD1  = (float*)p; p += align256(sizeof(float) * NN * HEADS);
    float* AS2  = (float*)p; p += align256(sizeof(float) * NN);
    float* AD2  = (float*)p; p += align256(sizeof(float) * NN);
    int*   DEG  = (int*)p;   p += align256(sizeof(int) * NN);
    int*   OFF  = (int*)p;   p += align256(sizeof(int) * (NN + 1));
    int*   CUR  = (int*)p;   p += align256(sizeof(int) * NN);
    int*   BSUM = (int*)p;   p += align256(sizeof(int) * NBLK);
    int*   BPRE = (int*)p;   p += align256(sizeof(int) * NBLK);
    int*   SIDX = (int*)p;   p += align256(sizeof(int) * (EE + NN));

    // CSR build + weight prep
    (void)hipMemsetAsync(DEG, 0, sizeof(int) * NN, stream);
    w1t_kernel<<<dim3(D1 / 32, IN_DIM / 32), 256, 0, stream>>>(W1, W1Tb);
    w2t_kernel<<<48, 256, 0, stream>>>(W2, W2Tb);
    hist_kernel<<<(EE + 255) / 256, 256, 0, stream>>>(e_dst, DEG);
    scan1_kernel<<<NBLK, 256, 0, stream>>>(DEG, BSUM);
    scan2_kernel<<<1, 256, 0, stream>>>(BSUM, BPRE, OFF);
    scan3_kernel<<<NBLK, 256, 0, stream>>>(DEG, BPRE, OFF, CUR);
    scatter_kernel<<<(EE + NN + 255) / 256, 256, 0, stream>>>(e_src, e_dst, CUR, SIDX);

    // layer 1
    gemm1_kernel<<<(NN + G1_BM - 1) / G1_BM, 512, 0, stream>>>(x, W1Tb, att_src1, att_dst1, H1b, AS1, AD1);
    agg1_kernel<<<NN / 4, 256, 0, stream>>>((const uint32*)H1b, AS1, AD1, OFF, SIDX, b1, (uint32*)OUT1b);

    // layer 2
    gemm2_kernel<<<(NN + G2_ROWS - 1) / G2_ROWS, 256, 0, stream>>>(OUT1b, W2Tb, att_src2, att_dst2, H2b, AS2, AD2);
    agg2_kernel<<<NN / 4, 256, 0, stream>>>(H2b, AS2, AD2, OFF, SIDX, b2, out);
}